// Round 11
// baseline (688.160 us; speedup 1.0000x reference)
//
#include <hip/hip_runtime.h>
#include <hip/hip_bf16.h>

typedef unsigned short u16;
typedef unsigned int u32;
typedef short short8 __attribute__((ext_vector_type(8)));
typedef float fvec4 __attribute__((ext_vector_type(4)));

#define NR 8192
#define ED 512
#define PSTR 264

__device__ inline u16 f2bf(float f) {
    union { float f; unsigned u; } c; c.f = f;
    unsigned u = c.u;
    u += 0x7FFFu + ((u >> 16) & 1u);
    return (u16)(u >> 16);
}
__device__ inline float bf2f(u16 h) {
    union { unsigned u; float f; } c; c.u = ((unsigned)h) << 16; return c.f;
}
__device__ inline short8 load_cvt8(const float* p) {
    const fvec4* q = (const fvec4*)p;
    fvec4 a = q[0], b = q[1];
    short8 r;
    r[0] = (short)f2bf(a[0]); r[1] = (short)f2bf(a[1]);
    r[2] = (short)f2bf(a[2]); r[3] = (short)f2bf(a[3]);
    r[4] = (short)f2bf(b[0]); r[5] = (short)f2bf(b[1]);
    r[6] = (short)f2bf(b[2]); r[7] = (short)f2bf(b[3]);
    return r;
}
__device__ inline void gload16(const void* g, void* l) {
    __builtin_amdgcn_global_load_lds(
        (const __attribute__((address_space(1))) u32*)g,
        (__attribute__((address_space(3))) u32*)l, 16, 0, 0);
}

// T2 swizzle helpers (both-sides involution, 16B-chunk preserving).
#define SWZ_SCOL(lane) ((((lane) & 7) ^ ((lane) >> 3)) * 8)
#define SWZ_RD(col, row) ((col) ^ (((row) & 7) * 8))

// K0: one-shot f32 -> bf16 conversion of x and the three W's.
__global__ __launch_bounds__(256) void cvt_kernel(
    const float* __restrict__ x, const float* __restrict__ Wq,
    const float* __restrict__ Wk, const float* __restrict__ Wv,
    u16* __restrict__ xb, u16* __restrict__ wb)
{
    int tid = blockIdx.x * 256 + threadIdx.x;
    const float* src; u16* dst; int off;
    if (tid < 524288)      { src = x;  dst = xb;          off = tid; }
    else if (tid < 557056) { src = Wq; dst = wb;          off = tid - 524288; }
    else if (tid < 589824) { src = Wk; dst = wb + 262144; off = tid - 557056; }
    else                   { src = Wv; dst = wb + 524288; off = tid - 589824; }
    *(short8*)(dst + (size_t)off * 8) = load_cvt8(src + (size_t)off * 8);
}

// K1: 128x128-tile LDS-staged GEMM (swizzled): q,k row-major; k also transposed; v transposed.
__global__ __launch_bounds__(256, 3) void qkv_kernel(
    const u16* __restrict__ xb, const u16* __restrict__ wb,
    const float* __restrict__ bq, const float* __restrict__ bk, const float* __restrict__ bv,
    u16* __restrict__ qb, u16* __restrict__ kb, u16* __restrict__ kT, u16* __restrict__ vT)
{
    __shared__ u16 ldsA[128][64];
    __shared__ u16 ldsB[128][64];

    const int lane = threadIdx.x & 63;
    const int w = threadIdx.x >> 6;
    const int ln = lane & 15;
    const int kg = lane >> 4;
    const int wr = w >> 1, wc = w & 1;
    const int z = blockIdx.z;
    const int R0 = blockIdx.y * 128;
    const int C0 = blockIdx.x * 128;
    const int srow = lane >> 3;
    const int scol = SWZ_SCOL(lane);

    const u16* B = wb + (size_t)z * 262144;
    const float* bias = (z == 0) ? bq : (z == 1) ? bk : bv;

    fvec4 acc[4][4];
    #pragma unroll
    for (int m = 0; m < 4; ++m)
        #pragma unroll
        for (int n = 0; n < 4; ++n) acc[m][n] = (fvec4){0.f, 0.f, 0.f, 0.f};

    for (int kt = 0; kt < 8; ++kt) {
        const int k0 = kt * 64;
        __syncthreads();
        #pragma unroll
        for (int i = 0; i < 4; ++i) {
            const int ra = (i * 4 + w) * 8;
            gload16(xb + (size_t)(R0 + ra + srow) * ED + k0 + scol, &ldsA[ra][0]);
            gload16(B  + (size_t)(C0 + ra + srow) * ED + k0 + scol, &ldsB[ra][0]);
        }
        __syncthreads();
        short8 af[2][4], bf8[2][4];
        #pragma unroll
        for (int kk = 0; kk < 2; ++kk) {
            #pragma unroll
            for (int m = 0; m < 4; ++m) {
                const int row = wr * 64 + m * 16 + ln;
                af[kk][m] = *(const short8*)&ldsA[row][SWZ_RD(kk * 32 + kg * 8, row)];
            }
            #pragma unroll
            for (int n = 0; n < 4; ++n) {
                const int row = wc * 64 + n * 16 + ln;
                bf8[kk][n] = *(const short8*)&ldsB[row][SWZ_RD(kk * 32 + kg * 8, row)];
            }
        }
        #pragma unroll
        for (int kk = 0; kk < 2; ++kk)
            #pragma unroll
            for (int m = 0; m < 4; ++m)
                #pragma unroll
                for (int n = 0; n < 4; ++n)
                    acc[m][n] = __builtin_amdgcn_mfma_f32_16x16x32_bf16(af[kk][m], bf8[kk][n], acc[m][n], 0, 0, 0);
    }

    #pragma unroll
    for (int n = 0; n < 4; ++n) {
        const int gcol = C0 + wc * 64 + n * 16 + ln;
        const float bc = bias[gcol];
        #pragma unroll
        for (int m = 0; m < 4; ++m) {
            #pragma unroll
            for (int r = 0; r < 4; ++r) {
                const int grow = R0 + wr * 64 + m * 16 + kg * 4 + r;
                u16 val = f2bf(acc[m][n][r] + bc);
                if (z == 0) {
                    qb[(size_t)grow * ED + gcol] = val;
                } else if (z == 1) {
                    kb[(size_t)grow * ED + gcol] = val;
                    kT[(size_t)gcol * NR + grow] = val;
                } else {
                    vT[(size_t)gcol * NR + grow] = val;
                }
            }
        }
    }
}

// K2: G = K^T K (512x512). One 16x16 tile per block; 4 waves split K 2048 each; LDS reduce.
__global__ __launch_bounds__(256) void gram_kernel(
    const u16* __restrict__ kT, u16* __restrict__ Gb)
{
    __shared__ float red[4][64][4];
    const int lane = threadIdx.x & 63;
    const int w = threadIdx.x >> 6;
    const int ln = lane & 15;
    const int kg = lane >> 4;
    const int i0 = (blockIdx.x >> 5) * 16, l0 = (blockIdx.x & 31) * 16;

    fvec4 acc[4];
    #pragma unroll
    for (int c = 0; c < 4; ++c) acc[c] = (fvec4){0.f, 0.f, 0.f, 0.f};
    const u16* arow = kT + (size_t)(i0 + ln) * NR + w * 2048 + kg * 8;
    const u16* brow = kT + (size_t)(l0 + ln) * NR + w * 2048 + kg * 8;
    #pragma unroll 8
    for (int t = 0; t < 64; ++t) {
        acc[t & 3] = __builtin_amdgcn_mfma_f32_16x16x32_bf16(
            *(const short8*)(arow + t * 32), *(const short8*)(brow + t * 32), acc[t & 3], 0, 0, 0);
    }
    fvec4 s = acc[0] + acc[1] + acc[2] + acc[3];
    #pragma unroll
    for (int r = 0; r < 4; ++r) red[w][lane][r] = s[r];
    __syncthreads();
    if (w == 0) {
        #pragma unroll
        for (int r = 0; r < 4; ++r) {
            float tot = red[0][lane][r] + red[1][lane][r] + red[2][lane][r] + red[3][lane][r];
            Gb[(size_t)(i0 + kg * 4 + r) * ED + l0 + ln] = f2bf(tot);
        }
    }
}

// K3: rn = 1/max(sqrt(q^T G q), eps). 512 blocks x 16 rows; 4 waves split the e-loop.
__global__ __launch_bounds__(256) void rn_kernel(
    const u16* __restrict__ qb, const u16* __restrict__ Gb, float* __restrict__ rn)
{
    __shared__ float red[4][16];
    const int lane = threadIdx.x & 63;
    const int wv = threadIdx.x >> 6;
    const int ln = lane & 15;
    const int kg = lane >> 4;
    const int m0 = blockIdx.x * 16;

    short8 afr[16];
    const u16* qrow = qb + (size_t)(m0 + ln) * ED + kg * 8;
    #pragma unroll
    for (int t = 0; t < 16; ++t) afr[t] = *(const short8*)(qrow + t * 32);

    float ss[4] = {0.f, 0.f, 0.f, 0.f};
    for (int ee = 0; ee < 8; ++ee) {
        const int e = wv * 8 + ee;
        fvec4 a0 = (fvec4){0.f, 0.f, 0.f, 0.f};
        fvec4 a1 = (fvec4){0.f, 0.f, 0.f, 0.f};
        const u16* grow = Gb + (size_t)(e * 16 + ln) * ED + kg * 8;
        #pragma unroll
        for (int t = 0; t < 16; t += 2) {
            a0 = __builtin_amdgcn_mfma_f32_16x16x32_bf16(afr[t],     *(const short8*)(grow + t * 32),       a0, 0, 0, 0);
            a1 = __builtin_amdgcn_mfma_f32_16x16x32_bf16(afr[t + 1], *(const short8*)(grow + (t + 1) * 32), a1, 0, 0, 0);
        }
        fvec4 acc = a0 + a1;
        #pragma unroll
        for (int r = 0; r < 4; ++r)
            ss[r] += acc[r] * bf2f(qb[(size_t)(m0 + kg * 4 + r) * ED + e * 16 + ln]);
    }
    #pragma unroll
    for (int r = 0; r < 4; ++r) {
        float v = ss[r];
        v += __shfl_xor(v, 1); v += __shfl_xor(v, 2);
        v += __shfl_xor(v, 4); v += __shfl_xor(v, 8);
        ss[r] = v;
    }
    if (ln == 0) {
        #pragma unroll
        for (int r = 0; r < 4; ++r) red[wv][kg * 4 + r] = ss[r];
    }
    __syncthreads();
    if (threadIdx.x < 16) {
        const int row = threadIdx.x;
        const float tot = red[0][row] + red[1][row] + red[2][row] + red[3][row];
        rn[m0 + row] = 1.0f / fmaxf(sqrtf(tot), 1e-12f);
    }
}

// K4: P = exp((Q K^T) * rn) bf16 + dsum row sums.
// NEW: 128(M)x256(N) tile, 512 threads (8 waves 2x4), LDS 48KB -> 3 blocks/CU
// = 24 waves/CU (2x R7's occupancy), -25% staging instrs. Natural tile order.
__global__ __launch_bounds__(512, 6) void sexp_kernel(
    const u16* __restrict__ qb, const u16* __restrict__ kb,
    const float* __restrict__ rn, u16* __restrict__ P, float* __restrict__ dsum)
{
    __shared__ u16 ldsA[128][64];
    __shared__ u16 ldsB[256][64];

    const int lane = threadIdx.x & 63;
    const int w = threadIdx.x >> 6;          // 0..7
    const int ln = lane & 15;
    const int kg = lane >> 4;
    const int wr = w >> 2, wc = w & 3;       // 2 x 4 wave grid
    const int R0 = blockIdx.y * 128;
    const int C0 = blockIdx.x * 256;
    const int srow = lane >> 3;
    const int scol = SWZ_SCOL(lane);

    fvec4 acc[4][4];
    #pragma unroll
    for (int m = 0; m < 4; ++m)
        #pragma unroll
        for (int n = 0; n < 4; ++n) acc[m][n] = (fvec4){0.f, 0.f, 0.f, 0.f};

    for (int kt = 0; kt < 8; ++kt) {
        const int k0 = kt * 64;
        __syncthreads();
        #pragma unroll
        for (int i = 0; i < 2; ++i) {
            const int ra = (i * 8 + w) * 8;
            gload16(qb + (size_t)(R0 + ra + srow) * ED + k0 + scol, &ldsA[ra][0]);
        }
        #pragma unroll
        for (int i = 0; i < 4; ++i) {
            const int rb = (i * 8 + w) * 8;
            gload16(kb + (size_t)(C0 + rb + srow) * ED + k0 + scol, &ldsB[rb][0]);
        }
        __syncthreads();
        short8 af[2][4], bf8[2][4];
        #pragma unroll
        for (int kk = 0; kk < 2; ++kk) {
            #pragma unroll
            for (int m = 0; m < 4; ++m) {
                const int row = wr * 64 + m * 16 + ln;
                af[kk][m] = *(const short8*)&ldsA[row][SWZ_RD(kk * 32 + kg * 8, row)];
            }
            #pragma unroll
            for (int n = 0; n < 4; ++n) {
                const int row = wc * 64 + n * 16 + ln;
                bf8[kk][n] = *(const short8*)&ldsB[row][SWZ_RD(kk * 32 + kg * 8, row)];
            }
        }
        #pragma unroll
        for (int kk = 0; kk < 2; ++kk)
            #pragma unroll
            for (int m = 0; m < 4; ++m)
                #pragma unroll
                for (int n = 0; n < 4; ++n)
                    acc[m][n] = __builtin_amdgcn_mfma_f32_16x16x32_bf16(af[kk][m], bf8[kk][n], acc[m][n], 0, 0, 0);
    }

    #pragma unroll
    for (int m = 0; m < 4; ++m) {
        float dpart[4] = {0.f, 0.f, 0.f, 0.f};
        #pragma unroll
        for (int r = 0; r < 4; ++r) {
            const int grow = R0 + wr * 64 + m * 16 + kg * 4 + r;
            const float rv = rn[grow];
            #pragma unroll
            for (int n = 0; n < 4; ++n) {
                const int gcol = C0 + wc * 64 + n * 16 + ln;
                u16 pb = f2bf(__expf(acc[m][n][r] * rv));
                P[(size_t)grow * NR + gcol] = pb;
                dpart[r] += bf2f(pb);
            }
        }
        #pragma unroll
        for (int r = 0; r < 4; ++r) {
            float v = dpart[r];
            v += __shfl_xor(v, 1); v += __shfl_xor(v, 2);
            v += __shfl_xor(v, 4); v += __shfl_xor(v, 8);
            if (ln == 0)
                atomicAdd(&dsum[R0 + wr * 64 + m * 16 + kg * 4 + r], v);
        }
    }
}

// K5: partial PV, 128x128 tiles, split-K (gridDim.z slabs), swizzled LDS, 4 blocks/CU.
// EXACT R7 configuration (BK=64, single buffer, 2 barriers/step).
__global__ __launch_bounds__(256, 4) void pv_kernel(
    const u16* __restrict__ P, const u16* __restrict__ vT, float* __restrict__ part,
    int ksteps)
{
    __shared__ u16 ldsA[128][64];
    __shared__ u16 ldsB[128][64];

    const int lane = threadIdx.x & 63;
    const int w = threadIdx.x >> 6;
    const int ln = lane & 15;
    const int kg = lane >> 4;
    const int wr = w >> 1, wc = w & 1;
    const int id2 = blockIdx.y * gridDim.x + blockIdx.x;  // 0..255 per z-slice
    const int tile = ((id2 & 7) << 5) + (id2 >> 3);
    const int R0 = (tile >> 2) * 128;
    const int C0 = (tile & 3) * 128;
    const int ks = blockIdx.z;
    const int srow = lane >> 3;
    const int scol = SWZ_SCOL(lane);

    float* pp = part + (size_t)ks * NR * ED;

    fvec4 acc[4][4];
    #pragma unroll
    for (int m = 0; m < 4; ++m)
        #pragma unroll
        for (int n = 0; n < 4; ++n) acc[m][n] = (fvec4){0.f, 0.f, 0.f, 0.f};

    for (int kt = 0; kt < ksteps; ++kt) {
        const int k0 = (ks * ksteps + kt) * 64;
        __syncthreads();
        #pragma unroll
        for (int i = 0; i < 4; ++i) {
            const int ra = (i * 4 + w) * 8;
            gload16(P  + (size_t)(R0 + ra + srow) * NR + k0 + scol, &ldsA[ra][0]);
            gload16(vT + (size_t)(C0 + ra + srow) * NR + k0 + scol, &ldsB[ra][0]);
        }
        __syncthreads();
        short8 af[2][4], bf8[2][4];
        #pragma unroll
        for (int kk = 0; kk < 2; ++kk) {
            #pragma unroll
            for (int m = 0; m < 4; ++m) {
                const int row = wr * 64 + m * 16 + ln;
                af[kk][m] = *(const short8*)&ldsA[row][SWZ_RD(kk * 32 + kg * 8, row)];
            }
            #pragma unroll
            for (int n = 0; n < 4; ++n) {
                const int row = wc * 64 + n * 16 + ln;
                bf8[kk][n] = *(const short8*)&ldsB[row][SWZ_RD(kk * 32 + kg * 8, row)];
            }
        }
        #pragma unroll
        for (int kk = 0; kk < 2; ++kk)
            #pragma unroll
            for (int m = 0; m < 4; ++m)
                #pragma unroll
                for (int n = 0; n < 4; ++n)
                    acc[m][n] = __builtin_amdgcn_mfma_f32_16x16x32_bf16(af[kk][m], bf8[kk][n], acc[m][n], 0, 0, 0);
    }

    #pragma unroll
    for (int m = 0; m < 4; ++m) {
        #pragma unroll
        for (int r = 0; r < 4; ++r) {
            const int grow = R0 + wr * 64 + m * 16 + kg * 4 + r;
            #pragma unroll
            for (int n = 0; n < 4; ++n) {
                const int gcol = C0 + wc * 64 + n * 16 + ln;
                pp[(size_t)grow * ED + gcol] = acc[m][n][r];
            }
        }
    }
}

// K6: out = (sum of nsplit partials) / dsum
__global__ __launch_bounds__(256) void reduce_kernel(
    const float* __restrict__ part, const float* __restrict__ dsum,
    float* __restrict__ out, int nsplit)
{
    const size_t idx = ((size_t)blockIdx.x * 256 + threadIdx.x) * 4;
    const int row = (int)(idx >> 9);
    const float iv = 1.0f / dsum[row];
    fvec4 s = *(const fvec4*)(part + idx);
    for (int k = 1; k < nsplit; ++k) {
        fvec4 b = *(const fvec4*)(part + (size_t)k * NR * ED + idx);
        #pragma unroll
        for (int i = 0; i < 4; ++i) s[i] += b[i];
    }
    fvec4 o;
    #pragma unroll
    for (int i = 0; i < 4; ++i) o[i] = s[i] * iv;
    *(fvec4*)(out + idx) = o;
}

// Fallback fused attention (R2 path) if ws is too small for P.
__global__ __launch_bounds__(512, 2) void attn_kernel(
    const u16* __restrict__ qb, const u16* __restrict__ kb,
    const u16* __restrict__ vT, const float* __restrict__ rn, float* __restrict__ out)
{
    __shared__ u16 p_lds[2 * 16 * PSTR];
    __shared__ float red[2][4][16];

    const int lane = threadIdx.x & 63;
    const int w = threadIdx.x >> 6;
    const int ln = lane & 15;
    const int kg = lane >> 4;
    const int rh = w >> 2;
    const int jg = w & 3;
    const int R0 = blockIdx.x * 32 + rh * 16;

    short8 afr[16];
    const u16* qrow = qb + (size_t)(R0 + ln) * ED + kg * 8;
    #pragma unroll
    for (int t = 0; t < 16; ++t) afr[t] = *(const short8*)(qrow + t * 32);

    float rnv[4];
    #pragma unroll
    for (int r = 0; r < 4; ++r) rnv[r] = rn[R0 + kg * 4 + r];

    fvec4 oacc[8];
    #pragma unroll
    for (int e = 0; e < 8; ++e) oacc[e] = (fvec4){0.f, 0.f, 0.f, 0.f};
    float dsum[4] = {0.f, 0.f, 0.f, 0.f};

    u16* pw = p_lds + rh * 16 * PSTR;

    for (int c = 0; c < 32; ++c) {
        const int j0 = c * 256 + jg * 64;
        fvec4 acc[4];
        #pragma unroll
        for (int jt = 0; jt < 4; ++jt) acc[jt] = (fvec4){0.f, 0.f, 0.f, 0.f};
        const u16* kbase = kb + (size_t)(j0 + ln) * ED + kg * 8;
        #pragma unroll 4
        for (int t = 0; t < 16; ++t) {
            short8 af = afr[t];
            #pragma unroll
            for (int jt = 0; jt < 4; ++jt) {
                short8 bfr = *(const short8*)(kbase + (size_t)jt * 16 * ED + t * 32);
                acc[jt] = __builtin_amdgcn_mfma_f32_16x16x32_bf16(af, bfr, acc[jt], 0, 0, 0);
            }
        }
        #pragma unroll
        for (int jt = 0; jt < 4; ++jt) {
            #pragma unroll
            for (int r = 0; r < 4; ++r) {
                float p = __expf(acc[jt][r] * rnv[r]);
                dsum[r] += p;
                pw[(kg * 4 + r) * PSTR + jg * 64 + jt * 16 + ln] = f2bf(p);
            }
        }
        __syncthreads();
        const u16* vbase = vT + (size_t)(jg * 128 + ln) * NR + c * 256 + kg * 8;
        const u16* prow = pw + ln * PSTR + kg * 8;
        #pragma unroll
        for (int kk = 0; kk < 8; ++kk) {
            short8 afp = *(const short8*)(prow + kk * 32);
            #pragma unroll
            for (int e = 0; e < 8; ++e) {
                short8 bfr = *(const short8*)(vbase + (size_t)e * 16 * NR + kk * 32);
                oacc[e] = __builtin_amdgcn_mfma_f32_16x16x32_bf16(afp, bfr, oacc[e], 0, 0, 0);
            }
        }
        __syncthreads();
    }

    #pragma unroll
    for (int r = 0; r < 4; ++r) {
        float v = dsum[r];
        v += __shfl_xor(v, 1); v += __shfl_xor(v, 2);
        v += __shfl_xor(v, 4); v += __shfl_xor(v, 8);
        dsum[r] = v;
    }
    if (ln == 0) {
        #pragma unroll
        for (int r = 0; r < 4; ++r) red[rh][jg][kg * 4 + r] = dsum[r];
    }
    __syncthreads();
    float inv[4];
    #pragma unroll
    for (int r = 0; r < 4; ++r) {
        const int row = kg * 4 + r;
        inv[r] = 1.0f / (red[rh][0][row] + red[rh][1][row] + red[rh][2][row] + red[rh][3][row]);
    }
    #pragma unroll
    for (int e = 0; e < 8; ++e) {
        #pragma unroll
        for (int r = 0; r < 4; ++r)
            out[(size_t)(R0 + kg * 4 + r) * ED + jg * 128 + e * 16 + ln] = oacc[e][r] * inv[r];
    }
}

extern "C" void kernel_launch(void* const* d_in, const int* in_sizes, int n_in,
                              void* d_out, int out_size, void* d_ws, size_t ws_size,
                              hipStream_t stream) {
    const float* x  = (const float*)d_in[0];
    const float* Wq = (const float*)d_in[1];
    const float* bq = (const float*)d_in[2];
    const float* Wk = (const float*)d_in[3];
    const float* bk = (const float*)d_in[4];
    const float* Wv = (const float*)d_in[5];
    const float* bv = (const float*)d_in[6];
    float* out = (float*)d_out;

    u16* xb = (u16*)d_ws;                          // 8 MB
    u16* wb = xb + (size_t)NR * ED;                // 1.5 MB
    u16* qb = wb + 3 * 262144;                     // 8 MB
    u16* kb = qb + (size_t)NR * ED;                // 8 MB
    u16* kT = kb + (size_t)NR * ED;                // 8 MB
    u16* vT = kT + (size_t)NR * ED;                // 8 MB  (byte offset 33.5 MB)
    u16* Gb = vT + (size_t)NR * ED;                // 0.5 MB
    float* rn   = (float*)(Gb + 262144);           // 32 KB
    float* dsum = rn + NR;                         // 32 KB
    u16* P = (u16*)(dsum + NR);                    // 128 MB

    const size_t need = (size_t)((u16*)(dsum + NR) - (u16*)d_ws) * 2 + (size_t)NR * NR * 2;
    const size_t need4 = need + (size_t)4 * NR * ED * sizeof(float);

    cvt_kernel<<<2432, 256, 0, stream>>>(x, Wq, Wk, Wv, xb, wb);
    dim3 g1(ED / 128, NR / 128, 3);
    qkv_kernel<<<g1, 256, 0, stream>>>(xb, wb, bq, bk, bv, qb, kb, kT, vT);
    gram_kernel<<<1024, 256, 0, stream>>>(kT, Gb);
    rn_kernel<<<512, 256, 0, stream>>>(qb, Gb, rn);

    if (ws_size >= need) {
        hipMemsetAsync(dsum, 0, NR * sizeof(float), stream);
        dim3 gs(NR / 256, NR / 128);
        sexp_kernel<<<gs, 512, 0, stream>>>(qb, kb, rn, P, dsum);

        int nsplit; float* part;
        if (ws_size >= need4) {
            nsplit = 4;
            part = (float*)(P + (size_t)NR * NR);          // after P
        } else {
            nsplit = 2;
            part = (float*)d_ws;                           // dead 32 MB region
        }
        dim3 gp(ED / 128, NR / 128, nsplit);
        pv_kernel<<<gp, 256, 0, stream>>>(P, vT, part, 128 / nsplit);
        reduce_kernel<<<NR * ED / 4 / 256, 256, 0, stream>>>(part, dsum, out, nsplit);
    } else {
        attn_kernel<<<NR / 32, 512, 0, stream>>>(qb, kb, vT, rn, out);
    }
}

// Round 12
// 355.365 us; speedup vs baseline: 1.9365x; 1.9365x over previous
//
#include <hip/hip_runtime.h>
#include <hip/hip_bf16.h>

typedef unsigned short u16;
typedef unsigned int u32;
typedef short short8 __attribute__((ext_vector_type(8)));
typedef float fvec4 __attribute__((ext_vector_type(4)));

#define NR 8192
#define ED 512
#define PSTR 264

__device__ inline u16 f2bf(float f) {
    union { float f; unsigned u; } c; c.f = f;
    unsigned u = c.u;
    u += 0x7FFFu + ((u >> 16) & 1u);
    return (u16)(u >> 16);
}
__device__ inline float bf2f(u16 h) {
    union { unsigned u; float f; } c; c.u = ((unsigned)h) << 16; return c.f;
}
__device__ inline short8 load_cvt8(const float* p) {
    const fvec4* q = (const fvec4*)p;
    fvec4 a = q[0], b = q[1];
    short8 r;
    r[0] = (short)f2bf(a[0]); r[1] = (short)f2bf(a[1]);
    r[2] = (short)f2bf(a[2]); r[3] = (short)f2bf(a[3]);
    r[4] = (short)f2bf(b[0]); r[5] = (short)f2bf(b[1]);
    r[6] = (short)f2bf(b[2]); r[7] = (short)f2bf(b[3]);
    return r;
}
__device__ inline void gload16(const void* g, void* l) {
    __builtin_amdgcn_global_load_lds(
        (const __attribute__((address_space(1))) u32*)g,
        (__attribute__((address_space(3))) u32*)l, 16, 0, 0);
}

// T2 swizzle helpers (both-sides involution, 16B-chunk preserving).
#define SWZ_SCOL(lane) ((((lane) & 7) ^ ((lane) >> 3)) * 8)
#define SWZ_RD(col, row) ((col) ^ (((row) & 7) * 8))

// K0: one-shot f32 -> bf16 conversion of x and the three W's.
__global__ __launch_bounds__(256) void cvt_kernel(
    const float* __restrict__ x, const float* __restrict__ Wq,
    const float* __restrict__ Wk, const float* __restrict__ Wv,
    u16* __restrict__ xb, u16* __restrict__ wb)
{
    int tid = blockIdx.x * 256 + threadIdx.x;
    const float* src; u16* dst; int off;
    if (tid < 524288)      { src = x;  dst = xb;          off = tid; }
    else if (tid < 557056) { src = Wq; dst = wb;          off = tid - 524288; }
    else if (tid < 589824) { src = Wk; dst = wb + 262144; off = tid - 557056; }
    else                   { src = Wv; dst = wb + 524288; off = tid - 589824; }
    *(short8*)(dst + (size_t)off * 8) = load_cvt8(src + (size_t)off * 8);
}

// K1: 128x128-tile LDS-staged GEMM (swizzled): q,k row-major; k also transposed; v transposed.
__global__ __launch_bounds__(256, 3) void qkv_kernel(
    const u16* __restrict__ xb, const u16* __restrict__ wb,
    const float* __restrict__ bq, const float* __restrict__ bk, const float* __restrict__ bv,
    u16* __restrict__ qb, u16* __restrict__ kb, u16* __restrict__ kT, u16* __restrict__ vT)
{
    __shared__ u16 ldsA[128][64];
    __shared__ u16 ldsB[128][64];

    const int lane = threadIdx.x & 63;
    const int w = threadIdx.x >> 6;
    const int ln = lane & 15;
    const int kg = lane >> 4;
    const int wr = w >> 1, wc = w & 1;
    const int z = blockIdx.z;
    const int R0 = blockIdx.y * 128;
    const int C0 = blockIdx.x * 128;
    const int srow = lane >> 3;
    const int scol = SWZ_SCOL(lane);

    const u16* B = wb + (size_t)z * 262144;
    const float* bias = (z == 0) ? bq : (z == 1) ? bk : bv;

    fvec4 acc[4][4];
    #pragma unroll
    for (int m = 0; m < 4; ++m)
        #pragma unroll
        for (int n = 0; n < 4; ++n) acc[m][n] = (fvec4){0.f, 0.f, 0.f, 0.f};

    for (int kt = 0; kt < 8; ++kt) {
        const int k0 = kt * 64;
        __syncthreads();
        #pragma unroll
        for (int i = 0; i < 4; ++i) {
            const int ra = (i * 4 + w) * 8;
            gload16(xb + (size_t)(R0 + ra + srow) * ED + k0 + scol, &ldsA[ra][0]);
            gload16(B  + (size_t)(C0 + ra + srow) * ED + k0 + scol, &ldsB[ra][0]);
        }
        __syncthreads();
        short8 af[2][4], bf8[2][4];
        #pragma unroll
        for (int kk = 0; kk < 2; ++kk) {
            #pragma unroll
            for (int m = 0; m < 4; ++m) {
                const int row = wr * 64 + m * 16 + ln;
                af[kk][m] = *(const short8*)&ldsA[row][SWZ_RD(kk * 32 + kg * 8, row)];
            }
            #pragma unroll
            for (int n = 0; n < 4; ++n) {
                const int row = wc * 64 + n * 16 + ln;
                bf8[kk][n] = *(const short8*)&ldsB[row][SWZ_RD(kk * 32 + kg * 8, row)];
            }
        }
        #pragma unroll
        for (int kk = 0; kk < 2; ++kk)
            #pragma unroll
            for (int m = 0; m < 4; ++m)
                #pragma unroll
                for (int n = 0; n < 4; ++n)
                    acc[m][n] = __builtin_amdgcn_mfma_f32_16x16x32_bf16(af[kk][m], bf8[kk][n], acc[m][n], 0, 0, 0);
    }

    #pragma unroll
    for (int n = 0; n < 4; ++n) {
        const int gcol = C0 + wc * 64 + n * 16 + ln;
        const float bc = bias[gcol];
        #pragma unroll
        for (int m = 0; m < 4; ++m) {
            #pragma unroll
            for (int r = 0; r < 4; ++r) {
                const int grow = R0 + wr * 64 + m * 16 + kg * 4 + r;
                u16 val = f2bf(acc[m][n][r] + bc);
                if (z == 0) {
                    qb[(size_t)grow * ED + gcol] = val;
                } else if (z == 1) {
                    kb[(size_t)grow * ED + gcol] = val;
                    kT[(size_t)gcol * NR + grow] = val;
                } else {
                    vT[(size_t)gcol * NR + grow] = val;
                }
            }
        }
    }
}

// K2: G = K^T K (512x512). One 16x16 tile per block; 4 waves split K 2048 each; LDS reduce.
__global__ __launch_bounds__(256) void gram_kernel(
    const u16* __restrict__ kT, u16* __restrict__ Gb)
{
    __shared__ float red[4][64][4];
    const int lane = threadIdx.x & 63;
    const int w = threadIdx.x >> 6;
    const int ln = lane & 15;
    const int kg = lane >> 4;
    const int i0 = (blockIdx.x >> 5) * 16, l0 = (blockIdx.x & 31) * 16;

    fvec4 acc[4];
    #pragma unroll
    for (int c = 0; c < 4; ++c) acc[c] = (fvec4){0.f, 0.f, 0.f, 0.f};
    const u16* arow = kT + (size_t)(i0 + ln) * NR + w * 2048 + kg * 8;
    const u16* brow = kT + (size_t)(l0 + ln) * NR + w * 2048 + kg * 8;
    #pragma unroll 8
    for (int t = 0; t < 64; ++t) {
        acc[t & 3] = __builtin_amdgcn_mfma_f32_16x16x32_bf16(
            *(const short8*)(arow + t * 32), *(const short8*)(brow + t * 32), acc[t & 3], 0, 0, 0);
    }
    fvec4 s = acc[0] + acc[1] + acc[2] + acc[3];
    #pragma unroll
    for (int r = 0; r < 4; ++r) red[w][lane][r] = s[r];
    __syncthreads();
    if (w == 0) {
        #pragma unroll
        for (int r = 0; r < 4; ++r) {
            float tot = red[0][lane][r] + red[1][lane][r] + red[2][lane][r] + red[3][lane][r];
            Gb[(size_t)(i0 + kg * 4 + r) * ED + l0 + ln] = f2bf(tot);
        }
    }
}

// K3: rn = 1/max(sqrt(q^T G q), eps). 512 blocks x 16 rows; 4 waves split the e-loop.
__global__ __launch_bounds__(256) void rn_kernel(
    const u16* __restrict__ qb, const u16* __restrict__ Gb, float* __restrict__ rn)
{
    __shared__ float red[4][16];
    const int lane = threadIdx.x & 63;
    const int wv = threadIdx.x >> 6;
    const int ln = lane & 15;
    const int kg = lane >> 4;
    const int m0 = blockIdx.x * 16;

    short8 afr[16];
    const u16* qrow = qb + (size_t)(m0 + ln) * ED + kg * 8;
    #pragma unroll
    for (int t = 0; t < 16; ++t) afr[t] = *(const short8*)(qrow + t * 32);

    float ss[4] = {0.f, 0.f, 0.f, 0.f};
    for (int ee = 0; ee < 8; ++ee) {
        const int e = wv * 8 + ee;
        fvec4 a0 = (fvec4){0.f, 0.f, 0.f, 0.f};
        fvec4 a1 = (fvec4){0.f, 0.f, 0.f, 0.f};
        const u16* grow = Gb + (size_t)(e * 16 + ln) * ED + kg * 8;
        #pragma unroll
        for (int t = 0; t < 16; t += 2) {
            a0 = __builtin_amdgcn_mfma_f32_16x16x32_bf16(afr[t],     *(const short8*)(grow + t * 32),       a0, 0, 0, 0);
            a1 = __builtin_amdgcn_mfma_f32_16x16x32_bf16(afr[t + 1], *(const short8*)(grow + (t + 1) * 32), a1, 0, 0, 0);
        }
        fvec4 acc = a0 + a1;
        #pragma unroll
        for (int r = 0; r < 4; ++r)
            ss[r] += acc[r] * bf2f(qb[(size_t)(m0 + kg * 4 + r) * ED + e * 16 + ln]);
    }
    #pragma unroll
    for (int r = 0; r < 4; ++r) {
        float v = ss[r];
        v += __shfl_xor(v, 1); v += __shfl_xor(v, 2);
        v += __shfl_xor(v, 4); v += __shfl_xor(v, 8);
        ss[r] = v;
    }
    if (ln == 0) {
        #pragma unroll
        for (int r = 0; r < 4; ++r) red[wv][kg * 4 + r] = ss[r];
    }
    __syncthreads();
    if (threadIdx.x < 16) {
        const int row = threadIdx.x;
        const float tot = red[0][row] + red[1][row] + red[2][row] + red[3][row];
        rn[m0 + row] = 1.0f / fmaxf(sqrtf(tot), 1e-12f);
    }
}

// K4: P = exp((Q K^T) * rn) bf16 + dsum row sums. EXACT R7 config:
// 128x128 tile, swizzled LDS, natural tile order, 3 blocks/CU, direct P store.
__global__ __launch_bounds__(256, 3) void sexp_kernel(
    const u16* __restrict__ qb, const u16* __restrict__ kb,
    const float* __restrict__ rn, u16* __restrict__ P, float* __restrict__ dsum)
{
    __shared__ u16 ldsA[128][64];
    __shared__ u16 ldsB[128][64];

    const int lane = threadIdx.x & 63;
    const int w = threadIdx.x >> 6;
    const int ln = lane & 15;
    const int kg = lane >> 4;
    const int wr = w >> 1, wc = w & 1;
    const int R0 = blockIdx.y * 128;
    const int C0 = blockIdx.x * 128;
    const int srow = lane >> 3;
    const int scol = SWZ_SCOL(lane);

    fvec4 acc[4][4];
    #pragma unroll
    for (int m = 0; m < 4; ++m)
        #pragma unroll
        for (int n = 0; n < 4; ++n) acc[m][n] = (fvec4){0.f, 0.f, 0.f, 0.f};

    for (int kt = 0; kt < 8; ++kt) {
        const int k0 = kt * 64;
        __syncthreads();
        #pragma unroll
        for (int i = 0; i < 4; ++i) {
            const int ra = (i * 4 + w) * 8;
            gload16(qb + (size_t)(R0 + ra + srow) * ED + k0 + scol, &ldsA[ra][0]);
            gload16(kb + (size_t)(C0 + ra + srow) * ED + k0 + scol, &ldsB[ra][0]);
        }
        __syncthreads();
        short8 af[2][4], bf8[2][4];
        #pragma unroll
        for (int kk = 0; kk < 2; ++kk) {
            #pragma unroll
            for (int m = 0; m < 4; ++m) {
                const int row = wr * 64 + m * 16 + ln;
                af[kk][m] = *(const short8*)&ldsA[row][SWZ_RD(kk * 32 + kg * 8, row)];
            }
            #pragma unroll
            for (int n = 0; n < 4; ++n) {
                const int row = wc * 64 + n * 16 + ln;
                bf8[kk][n] = *(const short8*)&ldsB[row][SWZ_RD(kk * 32 + kg * 8, row)];
            }
        }
        #pragma unroll
        for (int kk = 0; kk < 2; ++kk)
            #pragma unroll
            for (int m = 0; m < 4; ++m)
                #pragma unroll
                for (int n = 0; n < 4; ++n)
                    acc[m][n] = __builtin_amdgcn_mfma_f32_16x16x32_bf16(af[kk][m], bf8[kk][n], acc[m][n], 0, 0, 0);
    }

    #pragma unroll
    for (int m = 0; m < 4; ++m) {
        float dpart[4] = {0.f, 0.f, 0.f, 0.f};
        #pragma unroll
        for (int r = 0; r < 4; ++r) {
            const int grow = R0 + wr * 64 + m * 16 + kg * 4 + r;
            const float rv = rn[grow];
            #pragma unroll
            for (int n = 0; n < 4; ++n) {
                const int gcol = C0 + wc * 64 + n * 16 + ln;
                u16 pb = f2bf(__expf(acc[m][n][r] * rv));
                P[(size_t)grow * NR + gcol] = pb;
                dpart[r] += bf2f(pb);
            }
        }
        #pragma unroll
        for (int r = 0; r < 4; ++r) {
            float v = dpart[r];
            v += __shfl_xor(v, 1); v += __shfl_xor(v, 2);
            v += __shfl_xor(v, 4); v += __shfl_xor(v, 8);
            if (ln == 0)
                atomicAdd(&dsum[R0 + wr * 64 + m * 16 + kg * 4 + r], v);
        }
    }
}

// K5: PV, 128x128 tiles, split-K (gridDim.z slabs), swizzled LDS, 4 blocks/CU.
// R7 main loop; NEW epilogue: scale by 1/dsum and atomicAdd directly into out
// (out pre-zeroed) -- eliminates the part buffer and the reduce kernel.
__global__ __launch_bounds__(256, 4) void pv_kernel(
    const u16* __restrict__ P, const u16* __restrict__ vT,
    const float* __restrict__ dsum, float* __restrict__ out, int ksteps)
{
    __shared__ u16 ldsA[128][64];
    __shared__ u16 ldsB[128][64];

    const int lane = threadIdx.x & 63;
    const int w = threadIdx.x >> 6;
    const int ln = lane & 15;
    const int kg = lane >> 4;
    const int wr = w >> 1, wc = w & 1;
    const int id2 = blockIdx.y * gridDim.x + blockIdx.x;  // 0..255 per z-slice
    const int tile = ((id2 & 7) << 5) + (id2 >> 3);
    const int R0 = (tile >> 2) * 128;
    const int C0 = (tile & 3) * 128;
    const int ks = blockIdx.z;
    const int srow = lane >> 3;
    const int scol = SWZ_SCOL(lane);

    fvec4 acc[4][4];
    #pragma unroll
    for (int m = 0; m < 4; ++m)
        #pragma unroll
        for (int n = 0; n < 4; ++n) acc[m][n] = (fvec4){0.f, 0.f, 0.f, 0.f};

    for (int kt = 0; kt < ksteps; ++kt) {
        const int k0 = (ks * ksteps + kt) * 64;
        __syncthreads();
        #pragma unroll
        for (int i = 0; i < 4; ++i) {
            const int ra = (i * 4 + w) * 8;
            gload16(P  + (size_t)(R0 + ra + srow) * NR + k0 + scol, &ldsA[ra][0]);
            gload16(vT + (size_t)(C0 + ra + srow) * NR + k0 + scol, &ldsB[ra][0]);
        }
        __syncthreads();
        short8 af[2][4], bf8[2][4];
        #pragma unroll
        for (int kk = 0; kk < 2; ++kk) {
            #pragma unroll
            for (int m = 0; m < 4; ++m) {
                const int row = wr * 64 + m * 16 + ln;
                af[kk][m] = *(const short8*)&ldsA[row][SWZ_RD(kk * 32 + kg * 8, row)];
            }
            #pragma unroll
            for (int n = 0; n < 4; ++n) {
                const int row = wc * 64 + n * 16 + ln;
                bf8[kk][n] = *(const short8*)&ldsB[row][SWZ_RD(kk * 32 + kg * 8, row)];
            }
        }
        #pragma unroll
        for (int kk = 0; kk < 2; ++kk)
            #pragma unroll
            for (int m = 0; m < 4; ++m)
                #pragma unroll
                for (int n = 0; n < 4; ++n)
                    acc[m][n] = __builtin_amdgcn_mfma_f32_16x16x32_bf16(af[kk][m], bf8[kk][n], acc[m][n], 0, 0, 0);
    }

    #pragma unroll
    for (int m = 0; m < 4; ++m) {
        #pragma unroll
        for (int r = 0; r < 4; ++r) {
            const int grow = R0 + wr * 64 + m * 16 + kg * 4 + r;
            const float iv = 1.0f / dsum[grow];
            #pragma unroll
            for (int n = 0; n < 4; ++n) {
                const int gcol = C0 + wc * 64 + n * 16 + ln;
                atomicAdd(&out[(size_t)grow * ED + gcol], acc[m][n][r] * iv);
            }
        }
    }
}

// Fallback fused attention (R2 path) if ws is too small for P.
__global__ __launch_bounds__(512, 2) void attn_kernel(
    const u16* __restrict__ qb, const u16* __restrict__ kb,
    const u16* __restrict__ vT, const float* __restrict__ rn, float* __restrict__ out)
{
    __shared__ u16 p_lds[2 * 16 * PSTR];
    __shared__ float red[2][4][16];

    const int lane = threadIdx.x & 63;
    const int w = threadIdx.x >> 6;
    const int ln = lane & 15;
    const int kg = lane >> 4;
    const int rh = w >> 2;
    const int jg = w & 3;
    const int R0 = blockIdx.x * 32 + rh * 16;

    short8 afr[16];
    const u16* qrow = qb + (size_t)(R0 + ln) * ED + kg * 8;
    #pragma unroll
    for (int t = 0; t < 16; ++t) afr[t] = *(const short8*)(qrow + t * 32);

    float rnv[4];
    #pragma unroll
    for (int r = 0; r < 4; ++r) rnv[r] = rn[R0 + kg * 4 + r];

    fvec4 oacc[8];
    #pragma unroll
    for (int e = 0; e < 8; ++e) oacc[e] = (fvec4){0.f, 0.f, 0.f, 0.f};
    float dsum[4] = {0.f, 0.f, 0.f, 0.f};

    u16* pw = p_lds + rh * 16 * PSTR;

    for (int c = 0; c < 32; ++c) {
        const int j0 = c * 256 + jg * 64;
        fvec4 acc[4];
        #pragma unroll
        for (int jt = 0; jt < 4; ++jt) acc[jt] = (fvec4){0.f, 0.f, 0.f, 0.f};
        const u16* kbase = kb + (size_t)(j0 + ln) * ED + kg * 8;
        #pragma unroll 4
        for (int t = 0; t < 16; ++t) {
            short8 af = afr[t];
            #pragma unroll
            for (int jt = 0; jt < 4; ++jt) {
                short8 bfr = *(const short8*)(kbase + (size_t)jt * 16 * ED + t * 32);
                acc[jt] = __builtin_amdgcn_mfma_f32_16x16x32_bf16(af, bfr, acc[jt], 0, 0, 0);
            }
        }
        #pragma unroll
        for (int jt = 0; jt < 4; ++jt) {
            #pragma unroll
            for (int r = 0; r < 4; ++r) {
                float p = __expf(acc[jt][r] * rnv[r]);
                dsum[r] += p;
                pw[(kg * 4 + r) * PSTR + jg * 64 + jt * 16 + ln] = f2bf(p);
            }
        }
        __syncthreads();
        const u16* vbase = vT + (size_t)(jg * 128 + ln) * NR + c * 256 + kg * 8;
        const u16* prow = pw + ln * PSTR + kg * 8;
        #pragma unroll
        for (int kk = 0; kk < 8; ++kk) {
            short8 afp = *(const short8*)(prow + kk * 32);
            #pragma unroll
            for (int e = 0; e < 8; ++e) {
                short8 bfr = *(const short8*)(vbase + (size_t)e * 16 * NR + kk * 32);
                oacc[e] = __builtin_amdgcn_mfma_f32_16x16x32_bf16(afp, bfr, oacc[e], 0, 0, 0);
            }
        }
        __syncthreads();
    }

    #pragma unroll
    for (int r = 0; r < 4; ++r) {
        float v = dsum[r];
        v += __shfl_xor(v, 1); v += __shfl_xor(v, 2);
        v += __shfl_xor(v, 4); v += __shfl_xor(v, 8);
        dsum[r] = v;
    }
    if (ln == 0) {
        #pragma unroll
        for (int r = 0; r < 4; ++r) red[rh][jg][kg * 4 + r] = dsum[r];
    }
    __syncthreads();
    float inv[4];
    #pragma unroll
    for (int r = 0; r < 4; ++r) {
        const int row = kg * 4 + r;
        inv[r] = 1.0f / (red[rh][0][row] + red[rh][1][row] + red[rh][2][row] + red[rh][3][row]);
    }
    #pragma unroll
    for (int e = 0; e < 8; ++e) {
        #pragma unroll
        for (int r = 0; r < 4; ++r)
            out[(size_t)(R0 + kg * 4 + r) * ED + jg * 128 + e * 16 + ln] = oacc[e][r] * inv[r];
    }
}

extern "C" void kernel_launch(void* const* d_in, const int* in_sizes, int n_in,
                              void* d_out, int out_size, void* d_ws, size_t ws_size,
                              hipStream_t stream) {
    const float* x  = (const float*)d_in[0];
    const float* Wq = (const float*)d_in[1];
    const float* bq = (const float*)d_in[2];
    const float* Wk = (const float*)d_in[3];
    const float* bk = (const float*)d_in[4];
    const float* Wv = (const float*)d_in[5];
    const float* bv = (const float*)d_in[6];
    float* out = (float*)d_out;

    u16* xb = (u16*)d_ws;                          // 8 MB
    u16* wb = xb + (size_t)NR * ED;                // 1.5 MB
    u16* qb = wb + 3 * 262144;                     // 8 MB
    u16* kb = qb + (size_t)NR * ED;                // 8 MB
    u16* kT = kb + (size_t)NR * ED;                // 8 MB
    u16* vT = kT + (size_t)NR * ED;                // 8 MB  (byte offset 33.5 MB)
    u16* Gb = vT + (size_t)NR * ED;                // 0.5 MB
    float* rn   = (float*)(Gb + 262144);           // 32 KB
    float* dsum = rn + NR;                         // 32 KB
    u16* P = (u16*)(dsum + NR);                    // 128 MB

    const size_t need = (size_t)((u16*)(dsum + NR) - (u16*)d_ws) * 2 + (size_t)NR * NR * 2;

    cvt_kernel<<<2432, 256, 0, stream>>>(x, Wq, Wk, Wv, xb, wb);
    dim3 g1(ED / 128, NR / 128, 3);
    qkv_kernel<<<g1, 256, 0, stream>>>(xb, wb, bq, bk, bv, qb, kb, kT, vT);
    gram_kernel<<<1024, 256, 0, stream>>>(kT, Gb);
    rn_kernel<<<512, 256, 0, stream>>>(qb, Gb, rn);

    if (ws_size >= need) {
        hipMemsetAsync(dsum, 0, NR * sizeof(float), stream);
        hipMemsetAsync(out, 0, (size_t)NR * ED * sizeof(float), stream);
        dim3 gs(NR / 128, NR / 128);
        sexp_kernel<<<gs, 256, 0, stream>>>(qb, kb, rn, P, dsum);
        dim3 gp(ED / 128, NR / 128, 4);
        pv_kernel<<<gp, 256, 0, stream>>>(P, vT, dsum, out, 32);
    } else {
        attn_kernel<<<NR / 32, 512, 0, stream>>>(qb, kb, vT, rn, out);
    }
}

// Round 14
// 328.929 us; speedup vs baseline: 2.0921x; 1.0804x over previous
//
#include <hip/hip_runtime.h>
#include <hip/hip_bf16.h>

typedef unsigned short u16;
typedef unsigned int u32;
typedef short short8 __attribute__((ext_vector_type(8)));
typedef float fvec4 __attribute__((ext_vector_type(4)));

#define NR 8192
#define ED 512
#define PSTR 264

__device__ inline u16 f2bf(float f) {
    union { float f; unsigned u; } c; c.f = f;
    unsigned u = c.u;
    u += 0x7FFFu + ((u >> 16) & 1u);
    return (u16)(u >> 16);
}
__device__ inline float bf2f(u16 h) {
    union { unsigned u; float f; } c; c.u = ((unsigned)h) << 16; return c.f;
}
__device__ inline short8 load_cvt8(const float* p) {
    const fvec4* q = (const fvec4*)p;
    fvec4 a = q[0], b = q[1];
    short8 r;
    r[0] = (short)f2bf(a[0]); r[1] = (short)f2bf(a[1]);
    r[2] = (short)f2bf(a[2]); r[3] = (short)f2bf(a[3]);
    r[4] = (short)f2bf(b[0]); r[5] = (short)f2bf(b[1]);
    r[6] = (short)f2bf(b[2]); r[7] = (short)f2bf(b[3]);
    return r;
}
__device__ inline void gload16(const void* g, void* l) {
    __builtin_amdgcn_global_load_lds(
        (const __attribute__((address_space(1))) u32*)g,
        (__attribute__((address_space(3))) u32*)l, 16, 0, 0);
}

// T2 swizzle helpers (both-sides involution, 16B-chunk preserving).
#define SWZ_SCOL(lane) ((((lane) & 7) ^ ((lane) >> 3)) * 8)
#define SWZ_RD(col, row) ((col) ^ (((row) & 7) * 8))

// K0: one-shot f32 -> bf16 conversion of x and the three W's.
__global__ __launch_bounds__(256) void cvt_kernel(
    const float* __restrict__ x, const float* __restrict__ Wq,
    const float* __restrict__ Wk, const float* __restrict__ Wv,
    u16* __restrict__ xb, u16* __restrict__ wb)
{
    int tid = blockIdx.x * 256 + threadIdx.x;
    const float* src; u16* dst; int off;
    if (tid < 524288)      { src = x;  dst = xb;          off = tid; }
    else if (tid < 557056) { src = Wq; dst = wb;          off = tid - 524288; }
    else if (tid < 589824) { src = Wk; dst = wb + 262144; off = tid - 557056; }
    else                   { src = Wv; dst = wb + 524288; off = tid - 589824; }
    *(short8*)(dst + (size_t)off * 8) = load_cvt8(src + (size_t)off * 8);
}

// K1: 128x128-tile LDS-staged GEMM (swizzled): q,k row-major; k also transposed; v transposed.
__global__ __launch_bounds__(256, 3) void qkv_kernel(
    const u16* __restrict__ xb, const u16* __restrict__ wb,
    const float* __restrict__ bq, const float* __restrict__ bk, const float* __restrict__ bv,
    u16* __restrict__ qb, u16* __restrict__ kb, u16* __restrict__ kT, u16* __restrict__ vT)
{
    __shared__ u16 ldsA[128][64];
    __shared__ u16 ldsB[128][64];

    const int lane = threadIdx.x & 63;
    const int w = threadIdx.x >> 6;
    const int ln = lane & 15;
    const int kg = lane >> 4;
    const int wr = w >> 1, wc = w & 1;
    const int z = blockIdx.z;
    const int R0 = blockIdx.y * 128;
    const int C0 = blockIdx.x * 128;
    const int srow = lane >> 3;
    const int scol = SWZ_SCOL(lane);

    const u16* B = wb + (size_t)z * 262144;
    const float* bias = (z == 0) ? bq : (z == 1) ? bk : bv;

    fvec4 acc[4][4];
    #pragma unroll
    for (int m = 0; m < 4; ++m)
        #pragma unroll
        for (int n = 0; n < 4; ++n) acc[m][n] = (fvec4){0.f, 0.f, 0.f, 0.f};

    for (int kt = 0; kt < 8; ++kt) {
        const int k0 = kt * 64;
        __syncthreads();
        #pragma unroll
        for (int i = 0; i < 4; ++i) {
            const int ra = (i * 4 + w) * 8;
            gload16(xb + (size_t)(R0 + ra + srow) * ED + k0 + scol, &ldsA[ra][0]);
            gload16(B  + (size_t)(C0 + ra + srow) * ED + k0 + scol, &ldsB[ra][0]);
        }
        __syncthreads();
        short8 af[2][4], bf8[2][4];
        #pragma unroll
        for (int kk = 0; kk < 2; ++kk) {
            #pragma unroll
            for (int m = 0; m < 4; ++m) {
                const int row = wr * 64 + m * 16 + ln;
                af[kk][m] = *(const short8*)&ldsA[row][SWZ_RD(kk * 32 + kg * 8, row)];
            }
            #pragma unroll
            for (int n = 0; n < 4; ++n) {
                const int row = wc * 64 + n * 16 + ln;
                bf8[kk][n] = *(const short8*)&ldsB[row][SWZ_RD(kk * 32 + kg * 8, row)];
            }
        }
        #pragma unroll
        for (int kk = 0; kk < 2; ++kk)
            #pragma unroll
            for (int m = 0; m < 4; ++m)
                #pragma unroll
                for (int n = 0; n < 4; ++n)
                    acc[m][n] = __builtin_amdgcn_mfma_f32_16x16x32_bf16(af[kk][m], bf8[kk][n], acc[m][n], 0, 0, 0);
    }

    #pragma unroll
    for (int n = 0; n < 4; ++n) {
        const int gcol = C0 + wc * 64 + n * 16 + ln;
        const float bc = bias[gcol];
        #pragma unroll
        for (int m = 0; m < 4; ++m) {
            #pragma unroll
            for (int r = 0; r < 4; ++r) {
                const int grow = R0 + wr * 64 + m * 16 + kg * 4 + r;
                u16 val = f2bf(acc[m][n][r] + bc);
                if (z == 0) {
                    qb[(size_t)grow * ED + gcol] = val;
                } else if (z == 1) {
                    kb[(size_t)grow * ED + gcol] = val;
                    kT[(size_t)gcol * NR + grow] = val;
                } else {
                    vT[(size_t)gcol * NR + grow] = val;
                }
            }
        }
    }
}

// K2: G = K^T K (512x512). One 16x16 tile per block; 4 waves split K 2048 each; LDS reduce.
__global__ __launch_bounds__(256) void gram_kernel(
    const u16* __restrict__ kT, u16* __restrict__ Gb)
{
    __shared__ float red[4][64][4];
    const int lane = threadIdx.x & 63;
    const int w = threadIdx.x >> 6;
    const int ln = lane & 15;
    const int kg = lane >> 4;
    const int i0 = (blockIdx.x >> 5) * 16, l0 = (blockIdx.x & 31) * 16;

    fvec4 acc[4];
    #pragma unroll
    for (int c = 0; c < 4; ++c) acc[c] = (fvec4){0.f, 0.f, 0.f, 0.f};
    const u16* arow = kT + (size_t)(i0 + ln) * NR + w * 2048 + kg * 8;
    const u16* brow = kT + (size_t)(l0 + ln) * NR + w * 2048 + kg * 8;
    #pragma unroll 8
    for (int t = 0; t < 64; ++t) {
        acc[t & 3] = __builtin_amdgcn_mfma_f32_16x16x32_bf16(
            *(const short8*)(arow + t * 32), *(const short8*)(brow + t * 32), acc[t & 3], 0, 0, 0);
    }
    fvec4 s = acc[0] + acc[1] + acc[2] + acc[3];
    #pragma unroll
    for (int r = 0; r < 4; ++r) red[w][lane][r] = s[r];
    __syncthreads();
    if (w == 0) {
        #pragma unroll
        for (int r = 0; r < 4; ++r) {
            float tot = red[0][lane][r] + red[1][lane][r] + red[2][lane][r] + red[3][lane][r];
            Gb[(size_t)(i0 + kg * 4 + r) * ED + l0 + ln] = f2bf(tot);
        }
    }
}

// K3: rn = 1/max(sqrt(q^T G q), eps). 512 blocks x 16 rows; 4 waves split the e-loop.
__global__ __launch_bounds__(256) void rn_kernel(
    const u16* __restrict__ qb, const u16* __restrict__ Gb, float* __restrict__ rn)
{
    __shared__ float red[4][16];
    const int lane = threadIdx.x & 63;
    const int wv = threadIdx.x >> 6;
    const int ln = lane & 15;
    const int kg = lane >> 4;
    const int m0 = blockIdx.x * 16;

    short8 afr[16];
    const u16* qrow = qb + (size_t)(m0 + ln) * ED + kg * 8;
    #pragma unroll
    for (int t = 0; t < 16; ++t) afr[t] = *(const short8*)(qrow + t * 32);

    float ss[4] = {0.f, 0.f, 0.f, 0.f};
    for (int ee = 0; ee < 8; ++ee) {
        const int e = wv * 8 + ee;
        fvec4 a0 = (fvec4){0.f, 0.f, 0.f, 0.f};
        fvec4 a1 = (fvec4){0.f, 0.f, 0.f, 0.f};
        const u16* grow = Gb + (size_t)(e * 16 + ln) * ED + kg * 8;
        #pragma unroll
        for (int t = 0; t < 16; t += 2) {
            a0 = __builtin_amdgcn_mfma_f32_16x16x32_bf16(afr[t],     *(const short8*)(grow + t * 32),       a0, 0, 0, 0);
            a1 = __builtin_amdgcn_mfma_f32_16x16x32_bf16(afr[t + 1], *(const short8*)(grow + (t + 1) * 32), a1, 0, 0, 0);
        }
        fvec4 acc = a0 + a1;
        #pragma unroll
        for (int r = 0; r < 4; ++r)
            ss[r] += acc[r] * bf2f(qb[(size_t)(m0 + kg * 4 + r) * ED + e * 16 + ln]);
    }
    #pragma unroll
    for (int r = 0; r < 4; ++r) {
        float v = ss[r];
        v += __shfl_xor(v, 1); v += __shfl_xor(v, 2);
        v += __shfl_xor(v, 4); v += __shfl_xor(v, 8);
        ss[r] = v;
    }
    if (ln == 0) {
        #pragma unroll
        for (int r = 0; r < 4; ++r) red[wv][kg * 4 + r] = ss[r];
    }
    __syncthreads();
    if (threadIdx.x < 16) {
        const int row = threadIdx.x;
        const float tot = red[0][row] + red[1][row] + red[2][row] + red[3][row];
        rn[m0 + row] = 1.0f / fmaxf(sqrtf(tot), 1e-12f);
    }
}

// K4: P = exp((Q K^T) * rn) bf16 + dsum row sums. EXACT R7 config:
// 128x128 tile, swizzled LDS, natural tile order, 3 blocks/CU, direct P store.
__global__ __launch_bounds__(256, 3) void sexp_kernel(
    const u16* __restrict__ qb, const u16* __restrict__ kb,
    const float* __restrict__ rn, u16* __restrict__ P, float* __restrict__ dsum)
{
    __shared__ u16 ldsA[128][64];
    __shared__ u16 ldsB[128][64];

    const int lane = threadIdx.x & 63;
    const int w = threadIdx.x >> 6;
    const int ln = lane & 15;
    const int kg = lane >> 4;
    const int wr = w >> 1, wc = w & 1;
    const int R0 = blockIdx.y * 128;
    const int C0 = blockIdx.x * 128;
    const int srow = lane >> 3;
    const int scol = SWZ_SCOL(lane);

    fvec4 acc[4][4];
    #pragma unroll
    for (int m = 0; m < 4; ++m)
        #pragma unroll
        for (int n = 0; n < 4; ++n) acc[m][n] = (fvec4){0.f, 0.f, 0.f, 0.f};

    for (int kt = 0; kt < 8; ++kt) {
        const int k0 = kt * 64;
        __syncthreads();
        #pragma unroll
        for (int i = 0; i < 4; ++i) {
            const int ra = (i * 4 + w) * 8;
            gload16(qb + (size_t)(R0 + ra + srow) * ED + k0 + scol, &ldsA[ra][0]);
            gload16(kb + (size_t)(C0 + ra + srow) * ED + k0 + scol, &ldsB[ra][0]);
        }
        __syncthreads();
        short8 af[2][4], bf8[2][4];
        #pragma unroll
        for (int kk = 0; kk < 2; ++kk) {
            #pragma unroll
            for (int m = 0; m < 4; ++m) {
                const int row = wr * 64 + m * 16 + ln;
                af[kk][m] = *(const short8*)&ldsA[row][SWZ_RD(kk * 32 + kg * 8, row)];
            }
            #pragma unroll
            for (int n = 0; n < 4; ++n) {
                const int row = wc * 64 + n * 16 + ln;
                bf8[kk][n] = *(const short8*)&ldsB[row][SWZ_RD(kk * 32 + kg * 8, row)];
            }
        }
        #pragma unroll
        for (int kk = 0; kk < 2; ++kk)
            #pragma unroll
            for (int m = 0; m < 4; ++m)
                #pragma unroll
                for (int n = 0; n < 4; ++n)
                    acc[m][n] = __builtin_amdgcn_mfma_f32_16x16x32_bf16(af[kk][m], bf8[kk][n], acc[m][n], 0, 0, 0);
    }

    #pragma unroll
    for (int m = 0; m < 4; ++m) {
        float dpart[4] = {0.f, 0.f, 0.f, 0.f};
        #pragma unroll
        for (int r = 0; r < 4; ++r) {
            const int grow = R0 + wr * 64 + m * 16 + kg * 4 + r;
            const float rv = rn[grow];
            #pragma unroll
            for (int n = 0; n < 4; ++n) {
                const int gcol = C0 + wc * 64 + n * 16 + ln;
                u16 pb = f2bf(__expf(acc[m][n][r] * rv));
                P[(size_t)grow * NR + gcol] = pb;
                dpart[r] += bf2f(pb);
            }
        }
        #pragma unroll
        for (int r = 0; r < 4; ++r) {
            float v = dpart[r];
            v += __shfl_xor(v, 1); v += __shfl_xor(v, 2);
            v += __shfl_xor(v, 4); v += __shfl_xor(v, 8);
            if (ln == 0)
                atomicAdd(&dsum[R0 + wr * 64 + m * 16 + kg * 4 + r], v);
        }
    }
}

// K5a: partial PV, 128x256 output tile, 512 threads (8 waves 2x4), split-K=4.
// Halves P logical reads vs 128-wide tiles. LDS 48KB; grid (2,64,4)=512 blocks=2/CU.
__global__ __launch_bounds__(512, 4) void pv256_kernel(
    const u16* __restrict__ P, const u16* __restrict__ vT, float* __restrict__ part,
    int ksteps)
{
    __shared__ u16 ldsA[128][64];
    __shared__ u16 ldsB[256][64];

    const int lane = threadIdx.x & 63;
    const int w = threadIdx.x >> 6;          // 0..7
    const int ln = lane & 15;
    const int kg = lane >> 4;
    const int wr = w >> 2, wc = w & 3;       // 2 x 4 wave grid
    const int id2 = blockIdx.y * gridDim.x + blockIdx.x;   // 0..127 per z-slice
    const int tile = ((id2 & 7) << 4) + (id2 >> 3);        // XCD-chunked bijection (128 tiles)
    const int R0 = (tile >> 1) * 128;
    const int C0 = (tile & 1) * 256;
    const int ks = blockIdx.z;
    const int srow = lane >> 3;
    const int scol = SWZ_SCOL(lane);

    float* pp = part + (size_t)ks * NR * ED;

    fvec4 acc[4][4];
    #pragma unroll
    for (int m = 0; m < 4; ++m)
        #pragma unroll
        for (int n = 0; n < 4; ++n) acc[m][n] = (fvec4){0.f, 0.f, 0.f, 0.f};

    for (int kt = 0; kt < ksteps; ++kt) {
        const int k0 = (ks * ksteps + kt) * 64;
        __syncthreads();
        #pragma unroll
        for (int i = 0; i < 2; ++i) {
            const int ra = (i * 8 + w) * 8;
            gload16(P + (size_t)(R0 + ra + srow) * NR + k0 + scol, &ldsA[ra][0]);
        }
        #pragma unroll
        for (int i = 0; i < 4; ++i) {
            const int rb = (i * 8 + w) * 8;
            gload16(vT + (size_t)(C0 + rb + srow) * NR + k0 + scol, &ldsB[rb][0]);
        }
        __syncthreads();
        short8 af[2][4], bf8[2][4];
        #pragma unroll
        for (int kk = 0; kk < 2; ++kk) {
            #pragma unroll
            for (int m = 0; m < 4; ++m) {
                const int row = wr * 64 + m * 16 + ln;
                af[kk][m] = *(const short8*)&ldsA[row][SWZ_RD(kk * 32 + kg * 8, row)];
            }
            #pragma unroll
            for (int n = 0; n < 4; ++n) {
                const int row = wc * 64 + n * 16 + ln;
                bf8[kk][n] = *(const short8*)&ldsB[row][SWZ_RD(kk * 32 + kg * 8, row)];
            }
        }
        #pragma unroll
        for (int kk = 0; kk < 2; ++kk)
            #pragma unroll
            for (int m = 0; m < 4; ++m)
                #pragma unroll
                for (int n = 0; n < 4; ++n)
                    acc[m][n] = __builtin_amdgcn_mfma_f32_16x16x32_bf16(af[kk][m], bf8[kk][n], acc[m][n], 0, 0, 0);
    }

    #pragma unroll
    for (int m = 0; m < 4; ++m) {
        #pragma unroll
        for (int r = 0; r < 4; ++r) {
            const int grow = R0 + wr * 64 + m * 16 + kg * 4 + r;
            #pragma unroll
            for (int n = 0; n < 4; ++n) {
                const int gcol = C0 + wc * 64 + n * 16 + ln;
                pp[(size_t)grow * ED + gcol] = acc[m][n][r];
            }
        }
    }
}

// K5b: R7 pv (128x128, 256 threads) kept for the nsplit=2 fallback (avoids grid starvation).
__global__ __launch_bounds__(256, 4) void pv_kernel(
    const u16* __restrict__ P, const u16* __restrict__ vT, float* __restrict__ part,
    int ksteps)
{
    __shared__ u16 ldsA[128][64];
    __shared__ u16 ldsB[128][64];

    const int lane = threadIdx.x & 63;
    const int w = threadIdx.x >> 6;
    const int ln = lane & 15;
    const int kg = lane >> 4;
    const int wr = w >> 1, wc = w & 1;
    const int id2 = blockIdx.y * gridDim.x + blockIdx.x;
    const int tile = ((id2 & 7) << 5) + (id2 >> 3);
    const int R0 = (tile >> 2) * 128;
    const int C0 = (tile & 3) * 128;
    const int ks = blockIdx.z;
    const int srow = lane >> 3;
    const int scol = SWZ_SCOL(lane);

    float* pp = part + (size_t)ks * NR * ED;

    fvec4 acc[4][4];
    #pragma unroll
    for (int m = 0; m < 4; ++m)
        #pragma unroll
        for (int n = 0; n < 4; ++n) acc[m][n] = (fvec4){0.f, 0.f, 0.f, 0.f};

    for (int kt = 0; kt < ksteps; ++kt) {
        const int k0 = (ks * ksteps + kt) * 64;
        __syncthreads();
        #pragma unroll
        for (int i = 0; i < 4; ++i) {
            const int ra = (i * 4 + w) * 8;
            gload16(P  + (size_t)(R0 + ra + srow) * NR + k0 + scol, &ldsA[ra][0]);
            gload16(vT + (size_t)(C0 + ra + srow) * NR + k0 + scol, &ldsB[ra][0]);
        }
        __syncthreads();
        short8 af[2][4], bf8[2][4];
        #pragma unroll
        for (int kk = 0; kk < 2; ++kk) {
            #pragma unroll
            for (int m = 0; m < 4; ++m) {
                const int row = wr * 64 + m * 16 + ln;
                af[kk][m] = *(const short8*)&ldsA[row][SWZ_RD(kk * 32 + kg * 8, row)];
            }
            #pragma unroll
            for (int n = 0; n < 4; ++n) {
                const int row = wc * 64 + n * 16 + ln;
                bf8[kk][n] = *(const short8*)&ldsB[row][SWZ_RD(kk * 32 + kg * 8, row)];
            }
        }
        #pragma unroll
        for (int kk = 0; kk < 2; ++kk)
            #pragma unroll
            for (int m = 0; m < 4; ++m)
                #pragma unroll
                for (int n = 0; n < 4; ++n)
                    acc[m][n] = __builtin_amdgcn_mfma_f32_16x16x32_bf16(af[kk][m], bf8[kk][n], acc[m][n], 0, 0, 0);
    }

    #pragma unroll
    for (int m = 0; m < 4; ++m) {
        #pragma unroll
        for (int r = 0; r < 4; ++r) {
            const int grow = R0 + wr * 64 + m * 16 + kg * 4 + r;
            #pragma unroll
            for (int n = 0; n < 4; ++n) {
                const int gcol = C0 + wc * 64 + n * 16 + ln;
                pp[(size_t)grow * ED + gcol] = acc[m][n][r];
            }
        }
    }
}

// K6: out = (sum of nsplit partials) / dsum
__global__ __launch_bounds__(256) void reduce_kernel(
    const float* __restrict__ part, const float* __restrict__ dsum,
    float* __restrict__ out, int nsplit)
{
    const size_t idx = ((size_t)blockIdx.x * 256 + threadIdx.x) * 4;
    const int row = (int)(idx >> 9);
    const float iv = 1.0f / dsum[row];
    fvec4 s = *(const fvec4*)(part + idx);
    for (int k = 1; k < nsplit; ++k) {
        fvec4 b = *(const fvec4*)(part + (size_t)k * NR * ED + idx);
        #pragma unroll
        for (int i = 0; i < 4; ++i) s[i] += b[i];
    }
    fvec4 o;
    #pragma unroll
    for (int i = 0; i < 4; ++i) o[i] = s[i] * iv;
    *(fvec4*)(out + idx) = o;
}

// Fallback fused attention (R2 path) if ws is too small for P.
__global__ __launch_bounds__(512, 2) void attn_kernel(
    const u16* __restrict__ qb, const u16* __restrict__ kb,
    const u16* __restrict__ vT, const float* __restrict__ rn, float* __restrict__ out)
{
    __shared__ u16 p_lds[2 * 16 * PSTR];
    __shared__ float red[2][4][16];

    const int lane = threadIdx.x & 63;
    const int w = threadIdx.x >> 6;
    const int ln = lane & 15;
    const int kg = lane >> 4;
    const int rh = w >> 2;
    const int jg = w & 3;
    const int R0 = blockIdx.x * 32 + rh * 16;

    short8 afr[16];
    const u16* qrow = qb + (size_t)(R0 + ln) * ED + kg * 8;
    #pragma unroll
    for (int t = 0; t < 16; ++t) afr[t] = *(const short8*)(qrow + t * 32);

    float rnv[4];
    #pragma unroll
    for (int r = 0; r < 4; ++r) rnv[r] = rn[R0 + kg * 4 + r];

    fvec4 oacc[8];
    #pragma unroll
    for (int e = 0; e < 8; ++e) oacc[e] = (fvec4){0.f, 0.f, 0.f, 0.f};
    float dsum[4] = {0.f, 0.f, 0.f, 0.f};

    u16* pw = p_lds + rh * 16 * PSTR;

    for (int c = 0; c < 32; ++c) {
        const int j0 = c * 256 + jg * 64;
        fvec4 acc[4];
        #pragma unroll
        for (int jt = 0; jt < 4; ++jt) acc[jt] = (fvec4){0.f, 0.f, 0.f, 0.f};
        const u16* kbase = kb + (size_t)(j0 + ln) * ED + kg * 8;
        #pragma unroll 4
        for (int t = 0; t < 16; ++t) {
            short8 af = afr[t];
            #pragma unroll
            for (int jt = 0; jt < 4; ++jt) {
                short8 bfr = *(const short8*)(kbase + (size_t)jt * 16 * ED + t * 32);
                acc[jt] = __builtin_amdgcn_mfma_f32_16x16x32_bf16(af, bfr, acc[jt], 0, 0, 0);
            }
        }
        #pragma unroll
        for (int jt = 0; jt < 4; ++jt) {
            #pragma unroll
            for (int r = 0; r < 4; ++r) {
                float p = __expf(acc[jt][r] * rnv[r]);
                dsum[r] += p;
                pw[(kg * 4 + r) * PSTR + jg * 64 + jt * 16 + ln] = f2bf(p);
            }
        }
        __syncthreads();
        const u16* vbase = vT + (size_t)(jg * 128 + ln) * NR + c * 256 + kg * 8;
        const u16* prow = pw + ln * PSTR + kg * 8;
        #pragma unroll
        for (int kk = 0; kk < 8; ++kk) {
            short8 afp = *(const short8*)(prow + kk * 32);
            #pragma unroll
            for (int e = 0; e < 8; ++e) {
                short8 bfr = *(const short8*)(vbase + (size_t)e * 16 * NR + kk * 32);
                oacc[e] = __builtin_amdgcn_mfma_f32_16x16x32_bf16(afp, bfr, oacc[e], 0, 0, 0);
            }
        }
        __syncthreads();
    }

    #pragma unroll
    for (int r = 0; r < 4; ++r) {
        float v = dsum[r];
        v += __shfl_xor(v, 1); v += __shfl_xor(v, 2);
        v += __shfl_xor(v, 4); v += __shfl_xor(v, 8);
        dsum[r] = v;
    }
    if (ln == 0) {
        #pragma unroll
        for (int r = 0; r < 4; ++r) red[rh][jg][kg * 4 + r] = dsum[r];
    }
    __syncthreads();
    float inv[4];
    #pragma unroll
    for (int r = 0; r < 4; ++r) {
        const int row = kg * 4 + r;
        inv[r] = 1.0f / (red[rh][0][row] + red[rh][1][row] + red[rh][2][row] + red[rh][3][row]);
    }
    #pragma unroll
    for (int e = 0; e < 8; ++e) {
        #pragma unroll
        for (int r = 0; r < 4; ++r)
            out[(size_t)(R0 + kg * 4 + r) * ED + jg * 128 + e * 16 + ln] = oacc[e][r] * inv[r];
    }
}

extern "C" void kernel_launch(void* const* d_in, const int* in_sizes, int n_in,
                              void* d_out, int out_size, void* d_ws, size_t ws_size,
                              hipStream_t stream) {
    const float* x  = (const float*)d_in[0];
    const float* Wq = (const float*)d_in[1];
    const float* bq = (const float*)d_in[2];
    const float* Wk = (const float*)d_in[3];
    const float* bk = (const float*)d_in[4];
    const float* Wv = (const float*)d_in[5];
    const float* bv = (const float*)d_in[6];
    float* out = (float*)d_out;

    u16* xb = (u16*)d_ws;                          // 8 MB
    u16* wb = xb + (size_t)NR * ED;                // 1.5 MB
    u16* qb = wb + 3 * 262144;                     // 8 MB
    u16* kb = qb + (size_t)NR * ED;                // 8 MB
    u16* kT = kb + (size_t)NR * ED;                // 8 MB
    u16* vT = kT + (size_t)NR * ED;                // 8 MB  (byte offset 33.5 MB)
    u16* Gb = vT + (size_t)NR * ED;                // 0.5 MB
    float* rn   = (float*)(Gb + 262144);           // 32 KB
    float* dsum = rn + NR;                         // 32 KB
    u16* P = (u16*)(dsum + NR);                    // 128 MB

    const size_t need = (size_t)((u16*)(dsum + NR) - (u16*)d_ws) * 2 + (size_t)NR * NR * 2;
    const size_t need4 = need + (size_t)4 * NR * ED * sizeof(float);

    cvt_kernel<<<2432, 256, 0, stream>>>(x, Wq, Wk, Wv, xb, wb);
    dim3 g1(ED / 128, NR / 128, 3);
    qkv_kernel<<<g1, 256, 0, stream>>>(xb, wb, bq, bk, bv, qb, kb, kT, vT);
    gram_kernel<<<1024, 256, 0, stream>>>(kT, Gb);
    rn_kernel<<<512, 256, 0, stream>>>(qb, Gb, rn);

    if (ws_size >= need) {
        hipMemsetAsync(dsum, 0, NR * sizeof(float), stream);
        dim3 gs(NR / 128, NR / 128);
        sexp_kernel<<<gs, 256, 0, stream>>>(qb, kb, rn, P, dsum);

        if (ws_size >= need4) {
            float* part = (float*)(P + (size_t)NR * NR);   // after P
            dim3 gp(ED / 256, NR / 128, 4);
            pv256_kernel<<<gp, 512, 0, stream>>>(P, vT, part, 32);
            reduce_kernel<<<NR * ED / 4 / 256, 256, 0, stream>>>(part, dsum, out, 4);
        } else {
            float* part = (float*)d_ws;                    // dead 32 MB region
            dim3 gp(ED / 128, NR / 128, 2);
            pv_kernel<<<gp, 256, 0, stream>>>(P, vT, part, 64);
            reduce_kernel<<<NR * ED / 4 / 256, 256, 0, stream>>>(part, dsum, out, 2);
        }
    } else {
        attn_kernel<<<NR / 32, 512, 0, stream>>>(qb, kb, vT, rn, out);
    }
}

// Round 17
// 314.325 us; speedup vs baseline: 2.1893x; 1.0465x over previous
//
#include <hip/hip_runtime.h>
#include <hip/hip_bf16.h>

typedef unsigned short u16;
typedef unsigned int u32;
typedef short s4v __attribute__((ext_vector_type(4)));
typedef short short8 __attribute__((ext_vector_type(8)));
typedef float fvec4 __attribute__((ext_vector_type(4)));

#define NR 8192
#define ED 512
#define PSTR 264
#define TRP 136   // transposed-tile LDS row pitch (u16); 136*2=272B = 16B-aligned

__device__ inline u16 f2bf(float f) {
    union { float f; unsigned u; } c; c.f = f;
    unsigned u = c.u;
    u += 0x7FFFu + ((u >> 16) & 1u);
    return (u16)(u >> 16);
}
__device__ inline float bf2f(u16 h) {
    union { unsigned u; float f; } c; c.u = ((unsigned)h) << 16; return c.f;
}
__device__ inline short8 load_cvt8(const float* p) {
    const fvec4* q = (const fvec4*)p;
    fvec4 a = q[0], b = q[1];
    short8 r;
    r[0] = (short)f2bf(a[0]); r[1] = (short)f2bf(a[1]);
    r[2] = (short)f2bf(a[2]); r[3] = (short)f2bf(a[3]);
    r[4] = (short)f2bf(b[0]); r[5] = (short)f2bf(b[1]);
    r[6] = (short)f2bf(b[2]); r[7] = (short)f2bf(b[3]);
    return r;
}
__device__ inline void gload16(const void* g, void* l) {
    __builtin_amdgcn_global_load_lds(
        (const __attribute__((address_space(1))) u32*)g,
        (__attribute__((address_space(3))) u32*)l, 16, 0, 0);
}

// T2 swizzle helpers (both-sides involution, 16B-chunk preserving).
#define SWZ_SCOL(lane) ((((lane) & 7) ^ ((lane) >> 3)) * 8)
#define SWZ_RD(col, row) ((col) ^ (((row) & 7) * 8))

// K0: one-shot f32 -> bf16 conversion of x and the three W's.
__global__ __launch_bounds__(256) void cvt_kernel(
    const float* __restrict__ x, const float* __restrict__ Wq,
    const float* __restrict__ Wk, const float* __restrict__ Wv,
    u16* __restrict__ xb, u16* __restrict__ wb)
{
    int tid = blockIdx.x * 256 + threadIdx.x;
    const float* src; u16* dst; int off;
    if (tid < 524288)      { src = x;  dst = xb;          off = tid; }
    else if (tid < 557056) { src = Wq; dst = wb;          off = tid - 524288; }
    else if (tid < 589824) { src = Wk; dst = wb + 262144; off = tid - 557056; }
    else                   { src = Wv; dst = wb + 524288; off = tid - 589824; }
    *(short8*)(dst + (size_t)off * 8) = load_cvt8(src + (size_t)off * 8);
}

// K1: 128x128-tile LDS-staged GEMM (swizzled). q row-major direct;
// kb row-major + kT/vT via LDS-transposed tile -> contiguous 128B runs.
__global__ __launch_bounds__(256, 3) void qkv_kernel(
    const u16* __restrict__ xb, const u16* __restrict__ wb,
    const float* __restrict__ bq, const float* __restrict__ bk, const float* __restrict__ bv,
    u16* __restrict__ qb, u16* __restrict__ kb, u16* __restrict__ kT, u16* __restrict__ vT)
{
    __shared__ union {
        u16 stage[2][128][64];
        u16 tr[128 * TRP];
    } lds;

    const int lane = threadIdx.x & 63;
    const int w = threadIdx.x >> 6;
    const int ln = lane & 15;
    const int kg = lane >> 4;
    const int wr = w >> 1, wc = w & 1;
    const int z = blockIdx.z;
    const int R0 = blockIdx.y * 128;
    const int C0 = blockIdx.x * 128;
    const int srow = lane >> 3;
    const int scol = SWZ_SCOL(lane);

    const u16* B = wb + (size_t)z * 262144;
    const float* bias = (z == 0) ? bq : (z == 1) ? bk : bv;

    fvec4 acc[4][4];
    #pragma unroll
    for (int m = 0; m < 4; ++m)
        #pragma unroll
        for (int n = 0; n < 4; ++n) acc[m][n] = (fvec4){0.f, 0.f, 0.f, 0.f};

    for (int kt = 0; kt < 8; ++kt) {
        const int k0 = kt * 64;
        __syncthreads();
        #pragma unroll
        for (int i = 0; i < 4; ++i) {
            const int ra = (i * 4 + w) * 8;
            gload16(xb + (size_t)(R0 + ra + srow) * ED + k0 + scol, &lds.stage[0][ra][0]);
            gload16(B  + (size_t)(C0 + ra + srow) * ED + k0 + scol, &lds.stage[1][ra][0]);
        }
        __syncthreads();
        short8 af[2][4], bf8[2][4];
        #pragma unroll
        for (int kk = 0; kk < 2; ++kk) {
            #pragma unroll
            for (int m = 0; m < 4; ++m) {
                const int row = wr * 64 + m * 16 + ln;
                af[kk][m] = *(const short8*)&lds.stage[0][row][SWZ_RD(kk * 32 + kg * 8, row)];
            }
            #pragma unroll
            for (int n = 0; n < 4; ++n) {
                const int row = wc * 64 + n * 16 + ln;
                bf8[kk][n] = *(const short8*)&lds.stage[1][row][SWZ_RD(kk * 32 + kg * 8, row)];
            }
        }
        #pragma unroll
        for (int kk = 0; kk < 2; ++kk)
            #pragma unroll
            for (int m = 0; m < 4; ++m)
                #pragma unroll
                for (int n = 0; n < 4; ++n)
                    acc[m][n] = __builtin_amdgcn_mfma_f32_16x16x32_bf16(af[kk][m], bf8[kk][n], acc[m][n], 0, 0, 0);
    }

    if (z == 0) {
        // qb: row-major direct
        #pragma unroll
        for (int n = 0; n < 4; ++n) {
            const int gcol = C0 + wc * 64 + n * 16 + ln;
            const float bc = bias[gcol];
            #pragma unroll
            for (int m = 0; m < 4; ++m) {
                #pragma unroll
                for (int r = 0; r < 4; ++r) {
                    qb[(size_t)(R0 + wr * 64 + m * 16 + kg * 4 + r) * ED + gcol] = f2bf(acc[m][n][r] + bc);
                }
            }
        }
    } else {
        __syncthreads();   // all frag reads done; safe to reuse LDS as transpose buffer
        u16* dst = (z == 1) ? kT : vT;
        #pragma unroll
        for (int n = 0; n < 4; ++n) {
            const int col = wc * 64 + n * 16 + ln;      // tile col == dst row
            const float bc = bias[C0 + col];
            #pragma unroll
            for (int m = 0; m < 4; ++m) {
                const int row0 = wr * 64 + m * 16 + kg * 4;
                s4v pk;
                #pragma unroll
                for (int r = 0; r < 4; ++r) pk[r] = (short)f2bf(acc[m][n][r] + bc);
                *(s4v*)&lds.tr[col * TRP + row0] = pk;
                if (z == 1) {
                    #pragma unroll
                    for (int r = 0; r < 4; ++r) {
                        kb[(size_t)(R0 + row0 + r) * ED + C0 + col] = (u16)(unsigned short)pk[r];
                    }
                }
            }
        }
        __syncthreads();
        // coalesced transposed store: each thread owns 64 contiguous u16 of one dst row
        const int col = threadIdx.x & 127;
        const int half = threadIdx.x >> 7;
        u16* drow = dst + (size_t)(C0 + col) * NR + R0 + half * 64;
        const u16* srow2 = &lds.tr[col * TRP + half * 64];
        #pragma unroll
        for (int j = 0; j < 8; ++j) {
            *(short8*)&drow[j * 8] = *(const short8*)&srow2[j * 8];
        }
    }
}

// K2: G = K^T K (512x512). One 16x16 tile per block; 4 waves split K 2048 each; LDS reduce.
__global__ __launch_bounds__(256) void gram_kernel(
    const u16* __restrict__ kT, u16* __restrict__ Gb)
{
    __shared__ float red[4][64][4];
    const int lane = threadIdx.x & 63;
    const int w = threadIdx.x >> 6;
    const int ln = lane & 15;
    const int kg = lane >> 4;
    const int i0 = (blockIdx.x >> 5) * 16, l0 = (blockIdx.x & 31) * 16;

    fvec4 acc[4];
    #pragma unroll
    for (int c = 0; c < 4; ++c) acc[c] = (fvec4){0.f, 0.f, 0.f, 0.f};
    const u16* arow = kT + (size_t)(i0 + ln) * NR + w * 2048 + kg * 8;
    const u16* brow = kT + (size_t)(l0 + ln) * NR + w * 2048 + kg * 8;
    #pragma unroll 8
    for (int t = 0; t < 64; ++t) {
        acc[t & 3] = __builtin_amdgcn_mfma_f32_16x16x32_bf16(
            *(const short8*)(arow + t * 32), *(const short8*)(brow + t * 32), acc[t & 3], 0, 0, 0);
    }
    fvec4 s = acc[0] + acc[1] + acc[2] + acc[3];
    #pragma unroll
    for (int r = 0; r < 4; ++r) red[w][lane][r] = s[r];
    __syncthreads();
    if (w == 0) {
        #pragma unroll
        for (int r = 0; r < 4; ++r) {
            float tot = red[0][lane][r] + red[1][lane][r] + red[2][lane][r] + red[3][lane][r];
            Gb[(size_t)(i0 + kg * 4 + r) * ED + l0 + ln] = f2bf(tot);
        }
    }
}

// K3: rn = 1/max(sqrt(q^T G q), eps). 512 blocks x 16 rows; 4 waves split the e-loop.
__global__ __launch_bounds__(256) void rn_kernel(
    const u16* __restrict__ qb, const u16* __restrict__ Gb, float* __restrict__ rn)
{
    __shared__ float red[4][16];
    const int lane = threadIdx.x & 63;
    const int wv = threadIdx.x >> 6;
    const int ln = lane & 15;
    const int kg = lane >> 4;
    const int m0 = blockIdx.x * 16;

    short8 afr[16];
    const u16* qrow = qb + (size_t)(m0 + ln) * ED + kg * 8;
    #pragma unroll
    for (int t = 0; t < 16; ++t) afr[t] = *(const short8*)(qrow + t * 32);

    float ss[4] = {0.f, 0.f, 0.f, 0.f};
    for (int ee = 0; ee < 8; ++ee) {
        const int e = wv * 8 + ee;
        fvec4 a0 = (fvec4){0.f, 0.f, 0.f, 0.f};
        fvec4 a1 = (fvec4){0.f, 0.f, 0.f, 0.f};
        const u16* grow = Gb + (size_t)(e * 16 + ln) * ED + kg * 8;
        #pragma unroll
        for (int t = 0; t < 16; t += 2) {
            a0 = __builtin_amdgcn_mfma_f32_16x16x32_bf16(afr[t],     *(const short8*)(grow + t * 32),       a0, 0, 0, 0);
            a1 = __builtin_amdgcn_mfma_f32_16x16x32_bf16(afr[t + 1], *(const short8*)(grow + (t + 1) * 32), a1, 0, 0, 0);
        }
        fvec4 acc = a0 + a1;
        #pragma unroll
        for (int r = 0; r < 4; ++r)
            ss[r] += acc[r] * bf2f(qb[(size_t)(m0 + kg * 4 + r) * ED + e * 16 + ln]);
    }
    #pragma unroll
    for (int r = 0; r < 4; ++r) {
        float v = ss[r];
        v += __shfl_xor(v, 1); v += __shfl_xor(v, 2);
        v += __shfl_xor(v, 4); v += __shfl_xor(v, 8);
        ss[r] = v;
    }
    if (ln == 0) {
        #pragma unroll
        for (int r = 0; r < 4; ++r) red[wv][kg * 4 + r] = ss[r];
    }
    __syncthreads();
    if (threadIdx.x < 16) {
        const int row = threadIdx.x;
        const float tot = red[0][row] + red[1][row] + red[2][row] + red[3][row];
        rn[m0 + row] = 1.0f / fmaxf(sqrtf(tot), 1e-12f);
    }
}

// K4: P = exp((Q K^T) * rn) bf16 + dsum row sums. EXACT R7 config.
__global__ __launch_bounds__(256, 3) void sexp_kernel(
    const u16* __restrict__ qb, const u16* __restrict__ kb,
    const float* __restrict__ rn, u16* __restrict__ P, float* __restrict__ dsum)
{
    __shared__ u16 ldsA[128][64];
    __shared__ u16 ldsB[128][64];

    const int lane = threadIdx.x & 63;
    const int w = threadIdx.x >> 6;
    const int ln = lane & 15;
    const int kg = lane >> 4;
    const int wr = w >> 1, wc = w & 1;
    const int R0 = blockIdx.y * 128;
    const int C0 = blockIdx.x * 128;
    const int srow = lane >> 3;
    const int scol = SWZ_SCOL(lane);

    fvec4 acc[4][4];
    #pragma unroll
    for (int m = 0; m < 4; ++m)
        #pragma unroll
        for (int n = 0; n < 4; ++n) acc[m][n] = (fvec4){0.f, 0.f, 0.f, 0.f};

    for (int kt = 0; kt < 8; ++kt) {
        const int k0 = kt * 64;
        __syncthreads();
        #pragma unroll
        for (int i = 0; i < 4; ++i) {
            const int ra = (i * 4 + w) * 8;
            gload16(qb + (size_t)(R0 + ra + srow) * ED + k0 + scol, &ldsA[ra][0]);
            gload16(kb + (size_t)(C0 + ra + srow) * ED + k0 + scol, &ldsB[ra][0]);
        }
        __syncthreads();
        short8 af[2][4], bf8[2][4];
        #pragma unroll
        for (int kk = 0; kk < 2; ++kk) {
            #pragma unroll
            for (int m = 0; m < 4; ++m) {
                const int row = wr * 64 + m * 16 + ln;
                af[kk][m] = *(const short8*)&ldsA[row][SWZ_RD(kk * 32 + kg * 8, row)];
            }
            #pragma unroll
            for (int n = 0; n < 4; ++n) {
                const int row = wc * 64 + n * 16 + ln;
                bf8[kk][n] = *(const short8*)&ldsB[row][SWZ_RD(kk * 32 + kg * 8, row)];
            }
        }
        #pragma unroll
        for (int kk = 0; kk < 2; ++kk)
            #pragma unroll
            for (int m = 0; m < 4; ++m)
                #pragma unroll
                for (int n = 0; n < 4; ++n)
                    acc[m][n] = __builtin_amdgcn_mfma_f32_16x16x32_bf16(af[kk][m], bf8[kk][n], acc[m][n], 0, 0, 0);
    }

    #pragma unroll
    for (int m = 0; m < 4; ++m) {
        float dpart[4] = {0.f, 0.f, 0.f, 0.f};
        #pragma unroll
        for (int r = 0; r < 4; ++r) {
            const int grow = R0 + wr * 64 + m * 16 + kg * 4 + r;
            const float rv = rn[grow];
            #pragma unroll
            for (int n = 0; n < 4; ++n) {
                const int gcol = C0 + wc * 64 + n * 16 + ln;
                u16 pb = f2bf(__expf(acc[m][n][r] * rv));
                P[(size_t)grow * NR + gcol] = pb;
                dpart[r] += bf2f(pb);
            }
        }
        #pragma unroll
        for (int r = 0; r < 4; ++r) {
            float v = dpart[r];
            v += __shfl_xor(v, 1); v += __shfl_xor(v, 2);
            v += __shfl_xor(v, 4); v += __shfl_xor(v, 8);
            if (ln == 0)
                atomicAdd(&dsum[R0 + wr * 64 + m * 16 + kg * 4 + r], v);
        }
    }
}

// K5a: partial PV, 128x256 tile, 512 threads, split-K=4. Partials stored bf16.
__global__ __launch_bounds__(512, 4) void pv256_kernel(
    const u16* __restrict__ P, const u16* __restrict__ vT, u16* __restrict__ part,
    int ksteps)
{
    __shared__ u16 ldsA[128][64];
    __shared__ u16 ldsB[256][64];

    const int lane = threadIdx.x & 63;
    const int w = threadIdx.x >> 6;
    const int ln = lane & 15;
    const int kg = lane >> 4;
    const int wr = w >> 2, wc = w & 3;
    const int id2 = blockIdx.y * gridDim.x + blockIdx.x;
    const int tile = ((id2 & 7) << 4) + (id2 >> 3);
    const int R0 = (tile >> 1) * 128;
    const int C0 = (tile & 1) * 256;
    const int ks = blockIdx.z;
    const int srow = lane >> 3;
    const int scol = SWZ_SCOL(lane);

    u16* pp = part + (size_t)ks * NR * ED;

    fvec4 acc[4][4];
    #pragma unroll
    for (int m = 0; m < 4; ++m)
        #pragma unroll
        for (int n = 0; n < 4; ++n) acc[m][n] = (fvec4){0.f, 0.f, 0.f, 0.f};

    for (int kt = 0; kt < ksteps; ++kt) {
        const int k0 = (ks * ksteps + kt) * 64;
        __syncthreads();
        #pragma unroll
        for (int i = 0; i < 2; ++i) {
            const int ra = (i * 8 + w) * 8;
            gload16(P + (size_t)(R0 + ra + srow) * NR + k0 + scol, &ldsA[ra][0]);
        }
        #pragma unroll
        for (int i = 0; i < 4; ++i) {
            const int rb = (i * 8 + w) * 8;
            gload16(vT + (size_t)(C0 + rb + srow) * NR + k0 + scol, &ldsB[rb][0]);
        }
        __syncthreads();
        short8 af[2][4], bf8[2][4];
        #pragma unroll
        for (int kk = 0; kk < 2; ++kk) {
            #pragma unroll
            for (int m = 0; m < 4; ++m) {
                const int row = wr * 64 + m * 16 + ln;
                af[kk][m] = *(const short8*)&ldsA[row][SWZ_RD(kk * 32 + kg * 8, row)];
            }
            #pragma unroll
            for (int n = 0; n < 4; ++n) {
                const int row = wc * 64 + n * 16 + ln;
                bf8[kk][n] = *(const short8*)&ldsB[row][SWZ_RD(kk * 32 + kg * 8, row)];
            }
        }
        #pragma unroll
        for (int kk = 0; kk < 2; ++kk)
            #pragma unroll
            for (int m = 0; m < 4; ++m)
                #pragma unroll
                for (int n = 0; n < 4; ++n)
                    acc[m][n] = __builtin_amdgcn_mfma_f32_16x16x32_bf16(af[kk][m], bf8[kk][n], acc[m][n], 0, 0, 0);
    }

    #pragma unroll
    for (int m = 0; m < 4; ++m) {
        #pragma unroll
        for (int r = 0; r < 4; ++r) {
            const int grow = R0 + wr * 64 + m * 16 + kg * 4 + r;
            #pragma unroll
            for (int n = 0; n < 4; ++n) {
                const int gcol = C0 + wc * 64 + n * 16 + ln;
                pp[(size_t)grow * ED + gcol] = f2bf(acc[m][n][r]);
            }
        }
    }
}

// K5b: 128x128 pv for the nsplit=2 fallback. Partials bf16.
__global__ __launch_bounds__(256, 4) void pv_kernel(
    const u16* __restrict__ P, const u16* __restrict__ vT, u16* __restrict__ part,
    int ksteps)
{
    __shared__ u16 ldsA[128][64];
    __shared__ u16 ldsB[128][64];

    const int lane = threadIdx.x & 63;
    const int w = threadIdx.x >> 6;
    const int ln = lane & 15;
    const int kg = lane >> 4;
    const int wr = w >> 1, wc = w & 1;
    const int id2 = blockIdx.y * gridDim.x + blockIdx.x;
    const int tile = ((id2 & 7) << 5) + (id2 >> 3);
    const int R0 = (tile >> 2) * 128;
    const int C0 = (tile & 3) * 128;
    const int ks = blockIdx.z;
    const int srow = lane >> 3;
    const int scol = SWZ_SCOL(lane);

    u16* pp = part + (size_t)ks * NR * ED;

    fvec4 acc[4][4];
    #pragma unroll
    for (int m = 0; m < 4; ++m)
        #pragma unroll
        for (int n = 0; n < 4; ++n) acc[m][n] = (fvec4){0.f, 0.f, 0.f, 0.f};

    for (int kt = 0; kt < ksteps; ++kt) {
        const int k0 = (ks * ksteps + kt) * 64;
        __syncthreads();
        #pragma unroll
        for (int i = 0; i < 4; ++i) {
            const int ra = (i * 4 + w) * 8;
            gload16(P  + (size_t)(R0 + ra + srow) * NR + k0 + scol, &ldsA[ra][0]);
            gload16(vT + (size_t)(C0 + ra + srow) * NR + k0 + scol, &ldsB[ra][0]);
        }
        __syncthreads();
        short8 af[2][4], bf8[2][4];
        #pragma unroll
        for (int kk = 0; kk < 2; ++kk) {
            #pragma unroll
            for (int m = 0; m < 4; ++m) {
                const int row = wr * 64 + m * 16 + ln;
                af[kk][m] = *(const short8*)&ldsA[row][SWZ_RD(kk * 32 + kg * 8, row)];
            }
            #pragma unroll
            for (int n = 0; n < 4; ++n) {
                const int row = wc * 64 + n * 16 + ln;
                bf8[kk][n] = *(const short8*)&ldsB[row][SWZ_RD(kk * 32 + kg * 8, row)];
            }
        }
        #pragma unroll
        for (int kk = 0; kk < 2; ++kk)
            #pragma unroll
            for (int m = 0; m < 4; ++m)
                #pragma unroll
                for (int n = 0; n < 4; ++n)
                    acc[m][n] = __builtin_amdgcn_mfma_f32_16x16x32_bf16(af[kk][m], bf8[kk][n], acc[m][n], 0, 0, 0);
    }

    #pragma unroll
    for (int m = 0; m < 4; ++m) {
        #pragma unroll
        for (int r = 0; r < 4; ++r) {
            const int grow = R0 + wr * 64 + m * 16 + kg * 4 + r;
            #pragma unroll
            for (int n = 0; n < 4; ++n) {
                const int gcol = C0 + wc * 64 + n * 16 + ln;
                pp[(size_t)grow * ED + gcol] = f2bf(acc[m][n][r]);
            }
        }
    }
}

// K6: out = (sum of nsplit bf16 partials) / dsum. 8 elems/thread.
__global__ __launch_bounds__(256) void reduce_kernel(
    const u16* __restrict__ part, const float* __restrict__ dsum,
    float* __restrict__ out, int nsplit)
{
    const size_t idx = ((size_t)blockIdx.x * 256 + threadIdx.x) * 8;
    const int row = (int)(idx >> 9);
    const float iv = 1.0f / dsum[row];
    float s[8] = {0.f, 0.f, 0.f, 0.f, 0.f, 0.f, 0.f, 0.f};
    for (int k = 0; k < nsplit; ++k) {
        short8 v = *(const short8*)(part + (size_t)k * NR * ED + idx);
        #pragma unroll
        for (int i = 0; i < 8; ++i) s[i] += bf2f((u16)(unsigned short)v[i]);
    }
    fvec4 o0, o1;
    #pragma unroll
    for (int i = 0; i < 4; ++i) { o0[i] = s[i] * iv; o1[i] = s[i + 4] * iv; }
    *(fvec4*)(out + idx) = o0;
    *(fvec4*)(out + idx + 4) = o1;
}

// Fallback fused attention (R2 path) if ws is too small for P.
__global__ __launch_bounds__(512, 2) void attn_kernel(
    const u16* __restrict__ qb, const u16* __restrict__ kb,
    const u16* __restrict__ vT, const float* __restrict__ rn, float* __restrict__ out)
{
    __shared__ u16 p_lds[2 * 16 * PSTR];
    __shared__ float red[2][4][16];

    const int lane = threadIdx.x & 63;
    const int w = threadIdx.x >> 6;
    const int ln = lane & 15;
    const int kg = lane >> 4;
    const int rh = w >> 2;
    const int jg = w & 3;
    const int R0 = blockIdx.x * 32 + rh * 16;

    short8 afr[16];
    const u16* qrow = qb + (size_t)(R0 + ln) * ED + kg * 8;
    #pragma unroll
    for (int t = 0; t < 16; ++t) afr[t] = *(const short8*)(qrow + t * 32);

    float rnv[4];
    #pragma unroll
    for (int r = 0; r < 4; ++r) rnv[r] = rn[R0 + kg * 4 + r];

    fvec4 oacc[8];
    #pragma unroll
    for (int e = 0; e < 8; ++e) oacc[e] = (fvec4){0.f, 0.f, 0.f, 0.f};
    float dsum[4] = {0.f, 0.f, 0.f, 0.f};

    u16* pw = p_lds + rh * 16 * PSTR;

    for (int c = 0; c < 32; ++c) {
        const int j0 = c * 256 + jg * 64;
        fvec4 acc[4];
        #pragma unroll
        for (int jt = 0; jt < 4; ++jt) acc[jt] = (fvec4){0.f, 0.f, 0.f, 0.f};
        const u16* kbase = kb + (size_t)(j0 + ln) * ED + kg * 8;
        #pragma unroll 4
        for (int t = 0; t < 16; ++t) {
            short8 af = afr[t];
            #pragma unroll
            for (int jt = 0; jt < 4; ++jt) {
                short8 bfr = *(const short8*)(kbase + (size_t)jt * 16 * ED + t * 32);
                acc[jt] = __builtin_amdgcn_mfma_f32_16x16x32_bf16(af, bfr, acc[jt], 0, 0, 0);
            }
        }
        #pragma unroll
        for (int jt = 0; jt < 4; ++jt) {
            #pragma unroll
            for (int r = 0; r < 4; ++r) {
                float p = __expf(acc[jt][r] * rnv[r]);
                dsum[r] += p;
                pw[(kg * 4 + r) * PSTR + jg * 64 + jt * 16 + ln] = f2bf(p);
            }
        }
        __syncthreads();
        const u16* vbase = vT + (size_t)(jg * 128 + ln) * NR + c * 256 + kg * 8;
        const u16* prow = pw + ln * PSTR + kg * 8;
        #pragma unroll
        for (int kk = 0; kk < 8; ++kk) {
            short8 afp = *(const short8*)(prow + kk * 32);
            #pragma unroll
            for (int e = 0; e < 8; ++e) {
                short8 bfr = *(const short8*)(vbase + (size_t)e * 16 * NR + kk * 32);
                oacc[e] = __builtin_amdgcn_mfma_f32_16x16x32_bf16(afp, bfr, oacc[e], 0, 0, 0);
            }
        }
        __syncthreads();
    }

    #pragma unroll
    for (int r = 0; r < 4; ++r) {
        float v = dsum[r];
        v += __shfl_xor(v, 1); v += __shfl_xor(v, 2);
        v += __shfl_xor(v, 4); v += __shfl_xor(v, 8);
        dsum[r] = v;
    }
    if (ln == 0) {
        #pragma unroll
        for (int r = 0; r < 4; ++r) red[rh][jg][kg * 4 + r] = dsum[r];
    }
    __syncthreads();
    float inv[4];
    #pragma unroll
    for (int r = 0; r < 4; ++r) {
        const int row = kg * 4 + r;
        inv[r] = 1.0f / (red[rh][0][row] + red[rh][1][row] + red[rh][2][row] + red[rh][3][row]);
    }
    #pragma unroll
    for (int e = 0; e < 8; ++e) {
        #pragma unroll
        for (int r = 0; r < 4; ++r)
            out[(size_t)(R0 + kg * 4 + r) * ED + jg * 128 + e * 16 + ln] = oacc[e][r] * inv[r];
    }
}

extern "C" void kernel_launch(void* const* d_in, const int* in_sizes, int n_in,
                              void* d_out, int out_size, void* d_ws, size_t ws_size,
                              hipStream_t stream) {
    const float* x  = (const float*)d_in[0];
    const float* Wq = (const float*)d_in[1];
    const float* bq = (const float*)d_in[2];
    const float* Wk = (const float*)d_in[3];
    const float* bk = (const float*)d_in[4];
    const float* Wv = (const float*)d_in[5];
    const float* bv = (const float*)d_in[6];
    float* out = (float*)d_out;

    u16* xb = (u16*)d_ws;                          // 8 MB
    u16* wb = xb + (size_t)NR * ED;                // 1.5 MB
    u16* qb = wb + 3 * 262144;                     // 8 MB
    u16* kb = qb + (size_t)NR * ED;                // 8 MB
    u16* kT = kb + (size_t)NR * ED;                // 8 MB
    u16* vT = kT + (size_t)NR * ED;                // 8 MB  (byte offset 33.5 MB)
    u16* Gb = vT + (size_t)NR * ED;                // 0.5 MB
    float* rn   = (float*)(Gb + 262144);           // 32 KB
    float* dsum = rn + NR;                         // 32 KB
    u16* P = (u16*)(dsum + NR);                    // 128 MB

    const size_t need = (size_t)((u16*)(dsum + NR) - (u16*)d_ws) * 2 + (size_t)NR * NR * 2;
    const size_t need4 = need + (size_t)4 * NR * ED * sizeof(u16);

    cvt_kernel<<<2432, 256, 0, stream>>>(x, Wq, Wk, Wv, xb, wb);
    dim3 g1(ED / 128, NR / 128, 3);
    qkv_kernel<<<g1, 256, 0, stream>>>(xb, wb, bq, bk, bv, qb, kb, kT, vT);
    gram_kernel<<<1024, 256, 0, stream>>>(kT, Gb);
    rn_kernel<<<512, 256, 0, stream>>>(qb, Gb, rn);

    if (ws_size >= need) {
        hipMemsetAsync(dsum, 0, NR * sizeof(float), stream);
        dim3 gs(NR / 128, NR / 128);
        sexp_kernel<<<gs, 256, 0, stream>>>(qb, kb, rn, P, dsum);

        if (ws_size >= need4) {
            u16* part = P + (size_t)NR * NR;                // after P (bf16 slabs)
            dim3 gp(ED / 256, NR / 128, 4);
            pv256_kernel<<<gp, 512, 0, stream>>>(P, vT, part, 32);
            reduce_kernel<<<NR * ED / 8 / 256, 256, 0, stream>>>(part, dsum, out, 4);
        } else {
            u16* part = (u16*)d_ws;                        // dead 32 MB region
            dim3 gp(ED / 128, NR / 128, 2);
            pv_kernel<<<gp, 256, 0, stream>>>(P, vT, part, 64);
            reduce_kernel<<<NR * ED / 8 / 256, 256, 0, stream>>>(part, dsum, out, 2);
        }
    } else {
        attn_kernel<<<NR / 32, 512, 0, stream>>>(qb, kb, vT, rn, out);
    }
}

// Round 18
// 305.306 us; speedup vs baseline: 2.2540x; 1.0295x over previous
//
#include <hip/hip_runtime.h>
#include <hip/hip_bf16.h>

typedef unsigned short u16;
typedef unsigned int u32;
typedef short s4v __attribute__((ext_vector_type(4)));
typedef short short8 __attribute__((ext_vector_type(8)));
typedef float fvec4 __attribute__((ext_vector_type(4)));

#define NR 8192
#define ED 512
#define PSTR 264
#define TRP 136   // transposed-tile LDS row pitch (u16); 136*2=272B = 16B-aligned

__device__ inline u16 f2bf(float f) {
    union { float f; unsigned u; } c; c.f = f;
    unsigned u = c.u;
    u += 0x7FFFu + ((u >> 16) & 1u);
    return (u16)(u >> 16);
}
__device__ inline float bf2f(u16 h) {
    union { unsigned u; float f; } c; c.u = ((unsigned)h) << 16; return c.f;
}
__device__ inline short8 load_cvt8(const float* p) {
    const fvec4* q = (const fvec4*)p;
    fvec4 a = q[0], b = q[1];
    short8 r;
    r[0] = (short)f2bf(a[0]); r[1] = (short)f2bf(a[1]);
    r[2] = (short)f2bf(a[2]); r[3] = (short)f2bf(a[3]);
    r[4] = (short)f2bf(b[0]); r[5] = (short)f2bf(b[1]);
    r[6] = (short)f2bf(b[2]); r[7] = (short)f2bf(b[3]);
    return r;
}
__device__ inline void gload16(const void* g, void* l) {
    __builtin_amdgcn_global_load_lds(
        (const __attribute__((address_space(1))) u32*)g,
        (__attribute__((address_space(3))) u32*)l, 16, 0, 0);
}

// T2 swizzle helpers (both-sides involution, 16B-chunk preserving).
#define SWZ_SCOL(lane) ((((lane) & 7) ^ ((lane) >> 3)) * 8)
#define SWZ_RD(col, row) ((col) ^ (((row) & 7) * 8))

// K0: one-shot f32 -> bf16 conversion of x and the three W's.
__global__ __launch_bounds__(256) void cvt_kernel(
    const float* __restrict__ x, const float* __restrict__ Wq,
    const float* __restrict__ Wk, const float* __restrict__ Wv,
    u16* __restrict__ xb, u16* __restrict__ wb)
{
    int tid = blockIdx.x * 256 + threadIdx.x;
    const float* src; u16* dst; int off;
    if (tid < 524288)      { src = x;  dst = xb;          off = tid; }
    else if (tid < 557056) { src = Wq; dst = wb;          off = tid - 524288; }
    else if (tid < 589824) { src = Wk; dst = wb + 262144; off = tid - 557056; }
    else                   { src = Wv; dst = wb + 524288; off = tid - 589824; }
    *(short8*)(dst + (size_t)off * 8) = load_cvt8(src + (size_t)off * 8);
}

// K1: 128x128-tile LDS-staged GEMM (swizzled). q row-major direct;
// kb row-major + kT/vT via LDS-transposed tile -> contiguous 128B runs.
__global__ __launch_bounds__(256, 3) void qkv_kernel(
    const u16* __restrict__ xb, const u16* __restrict__ wb,
    const float* __restrict__ bq, const float* __restrict__ bk, const float* __restrict__ bv,
    u16* __restrict__ qb, u16* __restrict__ kb, u16* __restrict__ kT, u16* __restrict__ vT)
{
    __shared__ union {
        u16 stage[2][128][64];
        u16 tr[128 * TRP];
    } lds;

    const int lane = threadIdx.x & 63;
    const int w = threadIdx.x >> 6;
    const int ln = lane & 15;
    const int kg = lane >> 4;
    const int wr = w >> 1, wc = w & 1;
    const int z = blockIdx.z;
    const int R0 = blockIdx.y * 128;
    const int C0 = blockIdx.x * 128;
    const int srow = lane >> 3;
    const int scol = SWZ_SCOL(lane);

    const u16* B = wb + (size_t)z * 262144;
    const float* bias = (z == 0) ? bq : (z == 1) ? bk : bv;

    fvec4 acc[4][4];
    #pragma unroll
    for (int m = 0; m < 4; ++m)
        #pragma unroll
        for (int n = 0; n < 4; ++n) acc[m][n] = (fvec4){0.f, 0.f, 0.f, 0.f};

    for (int kt = 0; kt < 8; ++kt) {
        const int k0 = kt * 64;
        __syncthreads();
        #pragma unroll
        for (int i = 0; i < 4; ++i) {
            const int ra = (i * 4 + w) * 8;
            gload16(xb + (size_t)(R0 + ra + srow) * ED + k0 + scol, &lds.stage[0][ra][0]);
            gload16(B  + (size_t)(C0 + ra + srow) * ED + k0 + scol, &lds.stage[1][ra][0]);
        }
        __syncthreads();
        short8 af[2][4], bf8[2][4];
        #pragma unroll
        for (int kk = 0; kk < 2; ++kk) {
            #pragma unroll
            for (int m = 0; m < 4; ++m) {
                const int row = wr * 64 + m * 16 + ln;
                af[kk][m] = *(const short8*)&lds.stage[0][row][SWZ_RD(kk * 32 + kg * 8, row)];
            }
            #pragma unroll
            for (int n = 0; n < 4; ++n) {
                const int row = wc * 64 + n * 16 + ln;
                bf8[kk][n] = *(const short8*)&lds.stage[1][row][SWZ_RD(kk * 32 + kg * 8, row)];
            }
        }
        #pragma unroll
        for (int kk = 0; kk < 2; ++kk)
            #pragma unroll
            for (int m = 0; m < 4; ++m)
                #pragma unroll
                for (int n = 0; n < 4; ++n)
                    acc[m][n] = __builtin_amdgcn_mfma_f32_16x16x32_bf16(af[kk][m], bf8[kk][n], acc[m][n], 0, 0, 0);
    }

    if (z == 0) {
        #pragma unroll
        for (int n = 0; n < 4; ++n) {
            const int gcol = C0 + wc * 64 + n * 16 + ln;
            const float bc = bias[gcol];
            #pragma unroll
            for (int m = 0; m < 4; ++m) {
                #pragma unroll
                for (int r = 0; r < 4; ++r) {
                    qb[(size_t)(R0 + wr * 64 + m * 16 + kg * 4 + r) * ED + gcol] = f2bf(acc[m][n][r] + bc);
                }
            }
        }
    } else {
        __syncthreads();   // all frag reads done; safe to reuse LDS as transpose buffer
        u16* dst = (z == 1) ? kT : vT;
        #pragma unroll
        for (int n = 0; n < 4; ++n) {
            const int col = wc * 64 + n * 16 + ln;      // tile col == dst row
            const float bc = bias[C0 + col];
            #pragma unroll
            for (int m = 0; m < 4; ++m) {
                const int row0 = wr * 64 + m * 16 + kg * 4;
                s4v pk;
                #pragma unroll
                for (int r = 0; r < 4; ++r) pk[r] = (short)f2bf(acc[m][n][r] + bc);
                *(s4v*)&lds.tr[col * TRP + row0] = pk;
                if (z == 1) {
                    #pragma unroll
                    for (int r = 0; r < 4; ++r) {
                        kb[(size_t)(R0 + row0 + r) * ED + C0 + col] = (u16)(unsigned short)pk[r];
                    }
                }
            }
        }
        __syncthreads();
        const int col = threadIdx.x & 127;
        const int half = threadIdx.x >> 7;
        u16* drow = dst + (size_t)(C0 + col) * NR + R0 + half * 64;
        const u16* srow2 = &lds.tr[col * TRP + half * 64];
        #pragma unroll
        for (int j = 0; j < 8; ++j) {
            *(short8*)&drow[j * 8] = *(const short8*)&srow2[j * 8];
        }
    }
}

// K2: G = K^T K (512x512). One 16x16 tile per block; 4 waves split K 2048 each; LDS reduce.
__global__ __launch_bounds__(256) void gram_kernel(
    const u16* __restrict__ kT, u16* __restrict__ Gb)
{
    __shared__ float red[4][64][4];
    const int lane = threadIdx.x & 63;
    const int w = threadIdx.x >> 6;
    const int ln = lane & 15;
    const int kg = lane >> 4;
    const int i0 = (blockIdx.x >> 5) * 16, l0 = (blockIdx.x & 31) * 16;

    fvec4 acc[4];
    #pragma unroll
    for (int c = 0; c < 4; ++c) acc[c] = (fvec4){0.f, 0.f, 0.f, 0.f};
    const u16* arow = kT + (size_t)(i0 + ln) * NR + w * 2048 + kg * 8;
    const u16* brow = kT + (size_t)(l0 + ln) * NR + w * 2048 + kg * 8;
    #pragma unroll 8
    for (int t = 0; t < 64; ++t) {
        acc[t & 3] = __builtin_amdgcn_mfma_f32_16x16x32_bf16(
            *(const short8*)(arow + t * 32), *(const short8*)(brow + t * 32), acc[t & 3], 0, 0, 0);
    }
    fvec4 s = acc[0] + acc[1] + acc[2] + acc[3];
    #pragma unroll
    for (int r = 0; r < 4; ++r) red[w][lane][r] = s[r];
    __syncthreads();
    if (w == 0) {
        #pragma unroll
        for (int r = 0; r < 4; ++r) {
            float tot = red[0][lane][r] + red[1][lane][r] + red[2][lane][r] + red[3][lane][r];
            Gb[(size_t)(i0 + kg * 4 + r) * ED + l0 + ln] = f2bf(tot);
        }
    }
}

// K3: rn = 1/max(sqrt(q^T G q), eps). 512 blocks x 16 rows; 4 waves split the e-loop.
__global__ __launch_bounds__(256) void rn_kernel(
    const u16* __restrict__ qb, const u16* __restrict__ Gb, float* __restrict__ rn)
{
    __shared__ float red[4][16];
    const int lane = threadIdx.x & 63;
    const int wv = threadIdx.x >> 6;
    const int ln = lane & 15;
    const int kg = lane >> 4;
    const int m0 = blockIdx.x * 16;

    short8 afr[16];
    const u16* qrow = qb + (size_t)(m0 + ln) * ED + kg * 8;
    #pragma unroll
    for (int t = 0; t < 16; ++t) afr[t] = *(const short8*)(qrow + t * 32);

    float ss[4] = {0.f, 0.f, 0.f, 0.f};
    for (int ee = 0; ee < 8; ++ee) {
        const int e = wv * 8 + ee;
        fvec4 a0 = (fvec4){0.f, 0.f, 0.f, 0.f};
        fvec4 a1 = (fvec4){0.f, 0.f, 0.f, 0.f};
        const u16* grow = Gb + (size_t)(e * 16 + ln) * ED + kg * 8;
        #pragma unroll
        for (int t = 0; t < 16; t += 2) {
            a0 = __builtin_amdgcn_mfma_f32_16x16x32_bf16(afr[t],     *(const short8*)(grow + t * 32),       a0, 0, 0, 0);
            a1 = __builtin_amdgcn_mfma_f32_16x16x32_bf16(afr[t + 1], *(const short8*)(grow + (t + 1) * 32), a1, 0, 0, 0);
        }
        fvec4 acc = a0 + a1;
        #pragma unroll
        for (int r = 0; r < 4; ++r)
            ss[r] += acc[r] * bf2f(qb[(size_t)(m0 + kg * 4 + r) * ED + e * 16 + ln]);
    }
    #pragma unroll
    for (int r = 0; r < 4; ++r) {
        float v = ss[r];
        v += __shfl_xor(v, 1); v += __shfl_xor(v, 2);
        v += __shfl_xor(v, 4); v += __shfl_xor(v, 8);
        ss[r] = v;
    }
    if (ln == 0) {
        #pragma unroll
        for (int r = 0; r < 4; ++r) red[wv][kg * 4 + r] = ss[r];
    }
    __syncthreads();
    if (threadIdx.x < 16) {
        const int row = threadIdx.x;
        const float tot = red[0][row] + red[1][row] + red[2][row] + red[3][row];
        rn[m0 + row] = 1.0f / fmaxf(sqrtf(tot), 1e-12f);
    }
}

// K4: P = exp((Q K^T) * rn) bf16 + dsum row sums.
// NEW: 128(M)x256(N) tile, 512 threads (8 waves 2x4), LDS 48KB, (512,4) launch
// bounds (VGPR cap 128 -- R11's failure was the (512,6)=40-VGPR cap, not the tile).
// Natural x-major tile order preserved (L3-proven).
__global__ __launch_bounds__(512, 4) void sexp_kernel(
    const u16* __restrict__ qb, const u16* __restrict__ kb,
    const float* __restrict__ rn, u16* __restrict__ P, float* __restrict__ dsum)
{
    __shared__ u16 ldsA[128][64];
    __shared__ u16 ldsB[256][64];

    const int lane = threadIdx.x & 63;
    const int w = threadIdx.x >> 6;          // 0..7
    const int ln = lane & 15;
    const int kg = lane >> 4;
    const int wr = w >> 2, wc = w & 3;       // 2 x 4 wave grid
    const int R0 = blockIdx.y * 128;
    const int C0 = blockIdx.x * 256;
    const int srow = lane >> 3;
    const int scol = SWZ_SCOL(lane);

    fvec4 acc[4][4];
    #pragma unroll
    for (int m = 0; m < 4; ++m)
        #pragma unroll
        for (int n = 0; n < 4; ++n) acc[m][n] = (fvec4){0.f, 0.f, 0.f, 0.f};

    for (int kt = 0; kt < 8; ++kt) {
        const int k0 = kt * 64;
        __syncthreads();
        #pragma unroll
        for (int i = 0; i < 2; ++i) {
            const int ra = (i * 8 + w) * 8;
            gload16(qb + (size_t)(R0 + ra + srow) * ED + k0 + scol, &ldsA[ra][0]);
        }
        #pragma unroll
        for (int i = 0; i < 4; ++i) {
            const int rb = (i * 8 + w) * 8;
            gload16(kb + (size_t)(C0 + rb + srow) * ED + k0 + scol, &ldsB[rb][0]);
        }
        __syncthreads();
        short8 af[2][4], bf8[2][4];
        #pragma unroll
        for (int kk = 0; kk < 2; ++kk) {
            #pragma unroll
            for (int m = 0; m < 4; ++m) {
                const int row = wr * 64 + m * 16 + ln;
                af[kk][m] = *(const short8*)&ldsA[row][SWZ_RD(kk * 32 + kg * 8, row)];
            }
            #pragma unroll
            for (int n = 0; n < 4; ++n) {
                const int row = wc * 64 + n * 16 + ln;
                bf8[kk][n] = *(const short8*)&ldsB[row][SWZ_RD(kk * 32 + kg * 8, row)];
            }
        }
        #pragma unroll
        for (int kk = 0; kk < 2; ++kk)
            #pragma unroll
            for (int m = 0; m < 4; ++m)
                #pragma unroll
                for (int n = 0; n < 4; ++n)
                    acc[m][n] = __builtin_amdgcn_mfma_f32_16x16x32_bf16(af[kk][m], bf8[kk][n], acc[m][n], 0, 0, 0);
    }

    #pragma unroll
    for (int m = 0; m < 4; ++m) {
        float dpart[4] = {0.f, 0.f, 0.f, 0.f};
        #pragma unroll
        for (int r = 0; r < 4; ++r) {
            const int grow = R0 + wr * 64 + m * 16 + kg * 4 + r;
            const float rv = rn[grow];
            #pragma unroll
            for (int n = 0; n < 4; ++n) {
                const int gcol = C0 + wc * 64 + n * 16 + ln;
                u16 pb = f2bf(__expf(acc[m][n][r] * rv));
                P[(size_t)grow * NR + gcol] = pb;
                dpart[r] += bf2f(pb);
            }
        }
        #pragma unroll
        for (int r = 0; r < 4; ++r) {
            float v = dpart[r];
            v += __shfl_xor(v, 1); v += __shfl_xor(v, 2);
            v += __shfl_xor(v, 4); v += __shfl_xor(v, 8);
            if (ln == 0)
                atomicAdd(&dsum[R0 + wr * 64 + m * 16 + kg * 4 + r], v);
        }
    }
}

// K5a: partial PV, 128x256 tile, 512 threads, split-K=4. Partials stored bf16.
__global__ __launch_bounds__(512, 4) void pv256_kernel(
    const u16* __restrict__ P, const u16* __restrict__ vT, u16* __restrict__ part,
    int ksteps)
{
    __shared__ u16 ldsA[128][64];
    __shared__ u16 ldsB[256][64];

    const int lane = threadIdx.x & 63;
    const int w = threadIdx.x >> 6;
    const int ln = lane & 15;
    const int kg = lane >> 4;
    const int wr = w >> 2, wc = w & 3;
    const int id2 = blockIdx.y * gridDim.x + blockIdx.x;
    const int tile = ((id2 & 7) << 4) + (id2 >> 3);
    const int R0 = (tile >> 1) * 128;
    const int C0 = (tile & 1) * 256;
    const int ks = blockIdx.z;
    const int srow = lane >> 3;
    const int scol = SWZ_SCOL(lane);

    u16* pp = part + (size_t)ks * NR * ED;

    fvec4 acc[4][4];
    #pragma unroll
    for (int m = 0; m < 4; ++m)
        #pragma unroll
        for (int n = 0; n < 4; ++n) acc[m][n] = (fvec4){0.f, 0.f, 0.f, 0.f};

    for (int kt = 0; kt < ksteps; ++kt) {
        const int k0 = (ks * ksteps + kt) * 64;
        __syncthreads();
        #pragma unroll
        for (int i = 0; i < 2; ++i) {
            const int ra = (i * 8 + w) * 8;
            gload16(P + (size_t)(R0 + ra + srow) * NR + k0 + scol, &ldsA[ra][0]);
        }
        #pragma unroll
        for (int i = 0; i < 4; ++i) {
            const int rb = (i * 8 + w) * 8;
            gload16(vT + (size_t)(C0 + rb + srow) * NR + k0 + scol, &ldsB[rb][0]);
        }
        __syncthreads();
        short8 af[2][4], bf8[2][4];
        #pragma unroll
        for (int kk = 0; kk < 2; ++kk) {
            #pragma unroll
            for (int m = 0; m < 4; ++m) {
                const int row = wr * 64 + m * 16 + ln;
                af[kk][m] = *(const short8*)&ldsA[row][SWZ_RD(kk * 32 + kg * 8, row)];
            }
            #pragma unroll
            for (int n = 0; n < 4; ++n) {
                const int row = wc * 64 + n * 16 + ln;
                bf8[kk][n] = *(const short8*)&ldsB[row][SWZ_RD(kk * 32 + kg * 8, row)];
            }
        }
        #pragma unroll
        for (int kk = 0; kk < 2; ++kk)
            #pragma unroll
            for (int m = 0; m < 4; ++m)
                #pragma unroll
                for (int n = 0; n < 4; ++n)
                    acc[m][n] = __builtin_amdgcn_mfma_f32_16x16x32_bf16(af[kk][m], bf8[kk][n], acc[m][n], 0, 0, 0);
    }

    #pragma unroll
    for (int m = 0; m < 4; ++m) {
        #pragma unroll
        for (int r = 0; r < 4; ++r) {
            const int grow = R0 + wr * 64 + m * 16 + kg * 4 + r;
            #pragma unroll
            for (int n = 0; n < 4; ++n) {
                const int gcol = C0 + wc * 64 + n * 16 + ln;
                pp[(size_t)grow * ED + gcol] = f2bf(acc[m][n][r]);
            }
        }
    }
}

// K5b: 128x128 pv for the nsplit=2 fallback. Partials bf16.
__global__ __launch_bounds__(256, 4) void pv_kernel(
    const u16* __restrict__ P, const u16* __restrict__ vT, u16* __restrict__ part,
    int ksteps)
{
    __shared__ u16 ldsA[128][64];
    __shared__ u16 ldsB[128][64];

    const int lane = threadIdx.x & 63;
    const int w = threadIdx.x >> 6;
    const int ln = lane & 15;
    const int kg = lane >> 4;
    const int wr = w >> 1, wc = w & 1;
    const int id2 = blockIdx.y * gridDim.x + blockIdx.x;
    const int tile = ((id2 & 7) << 5) + (id2 >> 3);
    const int R0 = (tile >> 2) * 128;
    const int C0 = (tile & 3) * 128;
    const int ks = blockIdx.z;
    const int srow = lane >> 3;
    const int scol = SWZ_SCOL(lane);

    u16* pp = part + (size_t)ks * NR * ED;

    fvec4 acc[4][4];
    #pragma unroll
    for (int m = 0; m < 4; ++m)
        #pragma unroll
        for (int n = 0; n < 4; ++n) acc[m][n] = (fvec4){0.f, 0.f, 0.f, 0.f};

    for (int kt = 0; kt < ksteps; ++kt) {
        const int k0 = (ks * ksteps + kt) * 64;
        __syncthreads();
        #pragma unroll
        for (int i = 0; i < 4; ++i) {
            const int ra = (i * 4 + w) * 8;
            gload16(P  + (size_t)(R0 + ra + srow) * NR + k0 + scol, &ldsA[ra][0]);
            gload16(vT + (size_t)(C0 + ra + srow) * NR + k0 + scol, &ldsB[ra][0]);
        }
        __syncthreads();
        short8 af[2][4], bf8[2][4];
        #pragma unroll
        for (int kk = 0; kk < 2; ++kk) {
            #pragma unroll
            for (int m = 0; m < 4; ++m) {
                const int row = wr * 64 + m * 16 + ln;
                af[kk][m] = *(const short8*)&ldsA[row][SWZ_RD(kk * 32 + kg * 8, row)];
            }
            #pragma unroll
            for (int n = 0; n < 4; ++n) {
                const int row = wc * 64 + n * 16 + ln;
                bf8[kk][n] = *(const short8*)&ldsB[row][SWZ_RD(kk * 32 + kg * 8, row)];
            }
        }
        #pragma unroll
        for (int kk = 0; kk < 2; ++kk)
            #pragma unroll
            for (int m = 0; m < 4; ++m)
                #pragma unroll
                for (int n = 0; n < 4; ++n)
                    acc[m][n] = __builtin_amdgcn_mfma_f32_16x16x32_bf16(af[kk][m], bf8[kk][n], acc[m][n], 0, 0, 0);
    }

    #pragma unroll
    for (int m = 0; m < 4; ++m) {
        #pragma unroll
        for (int r = 0; r < 4; ++r) {
            const int grow = R0 + wr * 64 + m * 16 + kg * 4 + r;
            #pragma unroll
            for (int n = 0; n < 4; ++n) {
                const int gcol = C0 + wc * 64 + n * 16 + ln;
                pp[(size_t)grow * ED + gcol] = f2bf(acc[m][n][r]);
            }
        }
    }
}

// K6: out = (sum of nsplit bf16 partials) / dsum. 8 elems/thread.
__global__ __launch_bounds__(256) void reduce_kernel(
    const u16* __restrict__ part, const float* __restrict__ dsum,
    float* __restrict__ out, int nsplit)
{
    const size_t idx = ((size_t)blockIdx.x * 256 + threadIdx.x) * 8;
    const int row = (int)(idx >> 9);
    const float iv = 1.0f / dsum[row];
    float s[8] = {0.f, 0.f, 0.f, 0.f, 0.f, 0.f, 0.f, 0.f};
    for (int k = 0; k < nsplit; ++k) {
        short8 v = *(const short8*)(part + (size_t)k * NR * ED + idx);
        #pragma unroll
        for (int i = 0; i < 8; ++i) s[i] += bf2f((u16)(unsigned short)v[i]);
    }
    fvec4 o0, o1;
    #pragma unroll
    for (int i = 0; i < 4; ++i) { o0[i] = s[i] * iv; o1[i] = s[i + 4] * iv; }
    *(fvec4*)(out + idx) = o0;
    *(fvec4*)(out + idx + 4) = o1;
}

// Fallback fused attention (R2 path) if ws is too small for P.
__global__ __launch_bounds__(512, 2) void attn_kernel(
    const u16* __restrict__ qb, const u16* __restrict__ kb,
    const u16* __restrict__ vT, const float* __restrict__ rn, float* __restrict__ out)
{
    __shared__ u16 p_lds[2 * 16 * PSTR];
    __shared__ float red[2][4][16];

    const int lane = threadIdx.x & 63;
    const int w = threadIdx.x >> 6;
    const int ln = lane & 15;
    const int kg = lane >> 4;
    const int rh = w >> 2;
    const int jg = w & 3;
    const int R0 = blockIdx.x * 32 + rh * 16;

    short8 afr[16];
    const u16* qrow = qb + (size_t)(R0 + ln) * ED + kg * 8;
    #pragma unroll
    for (int t = 0; t < 16; ++t) afr[t] = *(const short8*)(qrow + t * 32);

    float rnv[4];
    #pragma unroll
    for (int r = 0; r < 4; ++r) rnv[r] = rn[R0 + kg * 4 + r];

    fvec4 oacc[8];
    #pragma unroll
    for (int e = 0; e < 8; ++e) oacc[e] = (fvec4){0.f, 0.f, 0.f, 0.f};
    float dsum[4] = {0.f, 0.f, 0.f, 0.f};

    u16* pw = p_lds + rh * 16 * PSTR;

    for (int c = 0; c < 32; ++c) {
        const int j0 = c * 256 + jg * 64;
        fvec4 acc[4];
        #pragma unroll
        for (int jt = 0; jt < 4; ++jt) acc[jt] = (fvec4){0.f, 0.f, 0.f, 0.f};
        const u16* kbase = kb + (size_t)(j0 + ln) * ED + kg * 8;
        #pragma unroll 4
        for (int t = 0; t < 16; ++t) {
            short8 af = afr[t];
            #pragma unroll
            for (int jt = 0; jt < 4; ++jt) {
                short8 bfr = *(const short8*)(kbase + (size_t)jt * 16 * ED + t * 32);
                acc[jt] = __builtin_amdgcn_mfma_f32_16x16x32_bf16(af, bfr, acc[jt], 0, 0, 0);
            }
        }
        #pragma unroll
        for (int jt = 0; jt < 4; ++jt) {
            #pragma unroll
            for (int r = 0; r < 4; ++r) {
                float p = __expf(acc[jt][r] * rnv[r]);
                dsum[r] += p;
                pw[(kg * 4 + r) * PSTR + jg * 64 + jt * 16 + ln] = f2bf(p);
            }
        }
        __syncthreads();
        const u16* vbase = vT + (size_t)(jg * 128 + ln) * NR + c * 256 + kg * 8;
        const u16* prow = pw + ln * PSTR + kg * 8;
        #pragma unroll
        for (int kk = 0; kk < 8; ++kk) {
            short8 afp = *(const short8*)(prow + kk * 32);
            #pragma unroll
            for (int e = 0; e < 8; ++e) {
                short8 bfr = *(const short8*)(vbase + (size_t)e * 16 * NR + kk * 32);
                oacc[e] = __builtin_amdgcn_mfma_f32_16x16x32_bf16(afp, bfr, oacc[e], 0, 0, 0);
            }
        }
        __syncthreads();
    }

    #pragma unroll
    for (int r = 0; r < 4; ++r) {
        float v = dsum[r];
        v += __shfl_xor(v, 1); v += __shfl_xor(v, 2);
        v += __shfl_xor(v, 4); v += __shfl_xor(v, 8);
        dsum[r] = v;
    }
    if (ln == 0) {
        #pragma unroll
        for (int r = 0; r < 4; ++r) red[rh][jg][kg * 4 + r] = dsum[r];
    }
    __syncthreads();
    float inv[4];
    #pragma unroll
    for (int r = 0; r < 4; ++r) {
        const int row = kg * 4 + r;
        inv[r] = 1.0f / (red[rh][0][row] + red[rh][1][row] + red[rh][2][row] + red[rh][3][row]);
    }
    #pragma unroll
    for (int e = 0; e < 8; ++e) {
        #pragma unroll
        for (int r = 0; r < 4; ++r)
            out[(size_t)(R0 + kg * 4 + r) * ED + jg * 128 + e * 16 + ln] = oacc[e][r] * inv[r];
    }
}

extern "C" void kernel_launch(void* const* d_in, const int* in_sizes, int n_in,
                              void* d_out, int out_size, void* d_ws, size_t ws_size,
                              hipStream_t stream) {
    const float* x  = (const float*)d_in[0];
    const float* Wq = (const float*)d_in[1];
    const float* bq = (const float*)d_in[2];
    const float* Wk = (const float*)d_in[3];
    const float* bk = (const float*)d_in[4];
    const float* Wv = (const float*)d_in[5];
    const float* bv = (const float*)d_in[6];
    float* out = (float*)d_out;

    u16* xb = (u16*)d_ws;                          // 8 MB
    u16* wb = xb + (size_t)NR * ED;                // 1.5 MB
    u16* qb = wb + 3 * 262144;                     // 8 MB
    u16* kb = qb + (size_t)NR * ED;                // 8 MB
    u16* kT = kb + (size_t)NR * ED;                // 8 MB
    u16* vT = kT + (size_t)NR * ED;                // 8 MB  (byte offset 33.5 MB)
    u16* Gb = vT + (size_t)NR * ED;                // 0.5 MB
    float* rn   = (float*)(Gb + 262144);           // 32 KB
    float* dsum = rn + NR;                         // 32 KB
    u16* P = (u16*)(dsum + NR);                    // 128 MB

    const size_t need = (size_t)((u16*)(dsum + NR) - (u16*)d_ws) * 2 + (size_t)NR * NR * 2;
    const size_t need4 = need + (size_t)4 * NR * ED * sizeof(u16);

    cvt_kernel<<<2432, 256, 0, stream>>>(x, Wq, Wk, Wv, xb, wb);
    dim3 g1(ED / 128, NR / 128, 3);
    qkv_kernel<<<g1, 256, 0, stream>>>(xb, wb, bq, bk, bv, qb, kb, kT, vT);
    gram_kernel<<<1024, 256, 0, stream>>>(kT, Gb);
    rn_kernel<<<512, 256, 0, stream>>>(qb, Gb, rn);

    if (ws_size >= need) {
        hipMemsetAsync(dsum, 0, NR * sizeof(float), stream);
        dim3 gs(NR / 256, NR / 128);
        sexp_kernel<<<gs, 512, 0, stream>>>(qb, kb, rn, P, dsum);

        if (ws_size >= need4) {
            u16* part = P + (size_t)NR * NR;                // after P (bf16 slabs)
            dim3 gp(ED / 256, NR / 128, 4);
            pv256_kernel<<<gp, 512, 0, stream>>>(P, vT, part, 32);
            reduce_kernel<<<NR * ED / 8 / 256, 256, 0, stream>>>(part, dsum, out, 4);
        } else {
            u16* part = (u16*)d_ws;                        // dead 32 MB region
            dim3 gp(ED / 128, NR / 128, 2);
            pv_kernel<<<gp, 256, 0, stream>>>(P, vT, part, 64);
            reduce_kernel<<<NR * ED / 8 / 256, 256, 0, stream>>>(part, dsum, out, 2);
        }
    } else {
        attn_kernel<<<NR / 32, 512, 0, stream>>>(qb, kb, vT, rn, out);
    }
}